// Round 11
// baseline (86.495 us; speedup 1.0000x reference)
//
#include <hip/hip_runtime.h>

#define NB 4
#define CD 256
#define HW 4096
#define KSG 32
#define CC (CD * CD)

typedef __attribute__((ext_vector_type(8))) short bf16x8;
typedef __attribute__((ext_vector_type(4))) float f32x4;

__device__ inline unsigned short f2bf(float x) {
  unsigned int u = __float_as_uint(x);
  unsigned int r = (u + 0x7FFFu + ((u >> 16) & 1u)) >> 16;
  return (unsigned short)r;
}
__device__ inline float bfhi(unsigned short h) {
  return __uint_as_float(((unsigned int)h) << 16);
}
__device__ __forceinline__ void gload16(const unsigned short* g, unsigned short* l) {
  __builtin_amdgcn_global_load_lds((const __attribute__((address_space(1))) void*)g,
                                   (__attribute__((address_space(3))) void*)l, 16, 0, 0);
}

// ---------- MFMA body (128-row A, 128-col B): A at sm[0]/sm[8192], B at sm[BOFF]/+8192 ----------
template <int BOFF>
__device__ __forceinline__ void mfma_body(const unsigned short* sm, f32x4 acc[4][2]) {
  int t = threadIdx.x, lane = t & 63, wid = t >> 6;
  int wr = wid >> 2, wc = wid & 3;
  int lrow = lane & 15, lkb = lane >> 4;
#pragma unroll
  for (int ks2 = 0; ks2 < 2; ++ks2) {
    bf16x8 ah[4], al[4], bh[2], bl[2];
#pragma unroll
    for (int m = 0; m < 4; ++m) {
      int r = wr * 64 + m * 16 + lrow;
      int sw = ((ks2 * 4 + lkb) ^ (r & 7)) * 8;
      ah[m] = *(const bf16x8*)(sm + r * 64 + sw);
      al[m] = *(const bf16x8*)(sm + 8192 + r * 64 + sw);
    }
#pragma unroll
    for (int q = 0; q < 2; ++q) {
      int r = wc * 32 + q * 16 + lrow;
      int sw = ((ks2 * 4 + lkb) ^ (r & 7)) * 8;
      bh[q] = *(const bf16x8*)(sm + BOFF + r * 64 + sw);
      bl[q] = *(const bf16x8*)(sm + BOFF + 8192 + r * 64 + sw);
    }
#pragma unroll
    for (int m = 0; m < 4; ++m)
#pragma unroll
      for (int q = 0; q < 2; ++q) {
        acc[m][q] = __builtin_amdgcn_mfma_f32_16x16x32_bf16(ah[m], bh[q], acc[m][q], 0, 0, 0);
        acc[m][q] = __builtin_amdgcn_mfma_f32_16x16x32_bf16(ah[m], bl[q], acc[m][q], 0, 0, 0);
        acc[m][q] = __builtin_amdgcn_mfma_f32_16x16x32_bf16(al[m], bh[q], acc[m][q], 0, 0, 0);
      }
  }
}

// ---------- bf16-operand NT core (gload16 staging; kD1/kD2) ----------
__device__ __forceinline__ void mfma_nt_core(
    const unsigned short* __restrict__ pH, const unsigned short* __restrict__ pL,
    const unsigned short* __restrict__ qH, const unsigned short* __restrict__ qL,
    int i0, int j0, unsigned short* sm, f32x4 acc[4][2]) {
  int t = threadIdx.x;
  int lane = t & 63, wid = t >> 6;
  int tsel = wid >> 1;
  int gbase = (wid & 1) * 8;
  const unsigned short* bp2 = (tsel == 0) ? pH : (tsel == 1) ? pL : (tsel == 2) ? qH : qL;
  int tb = (tsel < 2) ? i0 : j0;
  int rsub = lane >> 3;
  int gc = (lane & 7) ^ rsub;
  unsigned short* ldsT = sm + tsel * 8192;
#pragma unroll
  for (int m = 0; m < 4; ++m)
#pragma unroll
    for (int q = 0; q < 2; ++q) acc[m][q] = (f32x4){0.f, 0.f, 0.f, 0.f};
  for (int k0 = 0; k0 < 256; k0 += 64) {
#pragma unroll
    for (int s = 0; s < 8; ++s) {
      int g = gbase + s;
      gload16(bp2 + (size_t)(tb + g * 8 + rsub) * CD + k0 + gc * 8, ldsT + g * 512);
    }
    __syncthreads();
    mfma_body<16384>(sm, acc);
    __syncthreads();
  }
}

// ---------- gram core: operands from X fp32, reg-prefetch; DIAG stages A only ----------
template <bool DIAG, int NSTEP>
__device__ __forceinline__ void gram_core(const float* __restrict__ Xn, int i0, int j0,
                                          int kBegin, unsigned short* sm,
                                          f32x4 acc[4][2], float* __restrict__ psumRow) {
  int t = threadIdx.x;
  int r16 = t >> 4, k4 = (t & 15) * 4;
  int kg = k4 >> 3, kr = k4 & 7;
#pragma unroll
  for (int m = 0; m < 4; ++m)
#pragma unroll
    for (int q = 0; q < 2; ++q) acc[m][q] = (f32x4){0.f, 0.f, 0.f, 0.f};
  float ps[4] = {0.f, 0.f, 0.f, 0.f};
  float4 av[4], bv[4];
#pragma unroll
  for (int j = 0; j < 4; ++j) {
    av[j] = *(const float4*)(Xn + (size_t)(i0 + j * 32 + r16) * HW + kBegin + k4);
    if (!DIAG)
      bv[j] = *(const float4*)(Xn + (size_t)(j0 + j * 32 + r16) * HW + kBegin + k4);
  }
#pragma unroll
  for (int s = 0; s < NSTEP; ++s) {
    float4 av2[4], bv2[4];
    if (s < NSTEP - 1) {
#pragma unroll
      for (int j = 0; j < 4; ++j) {
        av2[j] = *(const float4*)(Xn + (size_t)(i0 + j * 32 + r16) * HW + kBegin +
                                  (s + 1) * 64 + k4);
        if (!DIAG)
          bv2[j] = *(const float4*)(Xn + (size_t)(j0 + j * 32 + r16) * HW + kBegin +
                                    (s + 1) * 64 + k4);
      }
    }
#pragma unroll
    for (int j = 0; j < 4; ++j) {
      int r = j * 32 + r16;
      int off = r * 64 + ((kg ^ (r & 7)) << 3) + kr;
      ushort4 h, l;
      h.x = f2bf(av[j].x); l.x = f2bf(av[j].x - bfhi(h.x));
      h.y = f2bf(av[j].y); l.y = f2bf(av[j].y - bfhi(h.y));
      h.z = f2bf(av[j].z); l.z = f2bf(av[j].z - bfhi(h.z));
      h.w = f2bf(av[j].w); l.w = f2bf(av[j].w - bfhi(h.w));
      *(ushort4*)(sm + off) = h;
      *(ushort4*)(sm + 8192 + off) = l;
      ps[j] += av[j].x + av[j].y + av[j].z + av[j].w;
      if (!DIAG) {
        h.x = f2bf(bv[j].x); l.x = f2bf(bv[j].x - bfhi(h.x));
        h.y = f2bf(bv[j].y); l.y = f2bf(bv[j].y - bfhi(h.y));
        h.z = f2bf(bv[j].z); l.z = f2bf(bv[j].z - bfhi(h.z));
        h.w = f2bf(bv[j].w); l.w = f2bf(bv[j].w - bfhi(h.w));
        *(ushort4*)(sm + 16384 + off) = h;
        *(ushort4*)(sm + 24576 + off) = l;
      }
    }
    __syncthreads();
    mfma_body<DIAG ? 0 : 16384>(sm, acc);
    __syncthreads();
    if (s < NSTEP - 1) {
#pragma unroll
      for (int j = 0; j < 4; ++j) {
        av[j] = av2[j];
        if (!DIAG) bv[j] = bv2[j];
      }
    }
  }
  if (psumRow) {
#pragma unroll
    for (int j = 0; j < 4; ++j) {
      float v = ps[j];
      v += __shfl_xor(v, 1); v += __shfl_xor(v, 2);
      v += __shfl_xor(v, 4); v += __shfl_xor(v, 8);
      if ((t & 15) == 0) psumRow[j * 32 + r16] = v;
    }
  }
}

// ---------- ROW-stage: LDS[r][k] = W[r0+r][k0+k] (hi/lo) ----------
__device__ __forceinline__ void stage_rowA(const float* __restrict__ W, int ld, int r0,
                                           int k0, unsigned short* dst) {
  int t = threadIdx.x;
  int r16 = t >> 4, k4 = (t & 15) * 4;
  int kg = k4 >> 3, kr = k4 & 7;
#pragma unroll
  for (int j = 0; j < 4; ++j) {
    int r = j * 32 + r16;
    float4 v = *(const float4*)(W + (size_t)(r0 + r) * ld + k0 + k4);
    int off = r * 64 + ((kg ^ (r & 7)) << 3) + kr;
    ushort4 h, l;
    h.x = f2bf(v.x); l.x = f2bf(v.x - bfhi(h.x));
    h.y = f2bf(v.y); l.y = f2bf(v.y - bfhi(h.y));
    h.z = f2bf(v.z); l.z = f2bf(v.z - bfhi(h.z));
    h.w = f2bf(v.w); l.w = f2bf(v.w - bfhi(h.w));
    *(ushort4*)(dst + off) = h;
    *(ushort4*)(dst + 8192 + off) = l;
  }
}

// ---------- COL-stage (transpose): LDS[c][k] = W[k0+k][c0+c] (hi/lo), 128 cols ----------
__device__ __forceinline__ void stage_colT(const float* __restrict__ W, int ld, int c0,
                                           int k0, unsigned short* dst) {
  int t = threadIdx.x;
#pragma unroll
  for (int ee = 0; ee < 8; ++ee) {
    int flat = ee * 512 + t;
    int c2 = flat >> 7, p = flat & 127;
    const float* src = W + (size_t)(k0 + 2 * c2) * ld + c0 + p;
    float xa = src[0], xb = src[ld];
    int c = 2 * c2;
    int off = p * 64 + ((((c >> 3)) ^ (p & 7)) << 3) + (c & 7);
    unsigned short ha = f2bf(xa), hb = f2bf(xb);
    ushort2 hv; hv.x = ha; hv.y = hb;
    ushort2 lv; lv.x = f2bf(xa - bfhi(ha)); lv.y = f2bf(xb - bfhi(hb));
    *(ushort2*)(dst + off) = hv;
    *(ushort2*)(dst + 8192 + off) = lv;
  }
}

// ---------- kF body: 256-row A (Ah@0, Al@16384), 32-col B (Bh@32768, Bl@34816) ----------
__device__ __forceinline__ void mfma_body_kf(const unsigned short* sm, f32x4 acc[2][2]) {
  int t = threadIdx.x, lane = t & 63, wid = t >> 6;
  int lrow = lane & 15, lkb = lane >> 4;
#pragma unroll
  for (int ks2 = 0; ks2 < 2; ++ks2) {
    bf16x8 ah[2], al[2], bh[2], bl[2];
#pragma unroll
    for (int m = 0; m < 2; ++m) {
      int r = wid * 32 + m * 16 + lrow;
      int sw = ((ks2 * 4 + lkb) ^ (r & 7)) * 8;
      ah[m] = *(const bf16x8*)(sm + r * 64 + sw);
      al[m] = *(const bf16x8*)(sm + 16384 + r * 64 + sw);
    }
#pragma unroll
    for (int q = 0; q < 2; ++q) {
      int p = q * 16 + lrow;
      int sw = ((ks2 * 4 + lkb) ^ (p & 7)) * 8;
      bh[q] = *(const bf16x8*)(sm + 32768 + p * 64 + sw);
      bl[q] = *(const bf16x8*)(sm + 34816 + p * 64 + sw);
    }
#pragma unroll
    for (int m = 0; m < 2; ++m)
#pragma unroll
      for (int q = 0; q < 2; ++q) {
        acc[m][q] = __builtin_amdgcn_mfma_f32_16x16x32_bf16(ah[m], bh[q], acc[m][q], 0, 0, 0);
        acc[m][q] = __builtin_amdgcn_mfma_f32_16x16x32_bf16(ah[m], bl[q], acc[m][q], 0, 0, 0);
        acc[m][q] = __builtin_amdgcn_mfma_f32_16x16x32_bf16(al[m], bh[q], acc[m][q], 0, 0, 0);
      }
  }
}

// ---------- kF core: A = At 256 rows via gload16; B = X fp32 32-col transpose-staged ----------
__device__ __forceinline__ void final_core256(const unsigned short* __restrict__ aH,
                                              const unsigned short* __restrict__ aL,
                                              const float* __restrict__ Xn, int j0,
                                              unsigned short* sm, f32x4 acc[2][2]) {
  int t = threadIdx.x, lane = t & 63, wid = t >> 6;
  const unsigned short* ap = (wid & 4) ? aL : aH;
  unsigned short* ldsA = sm + ((wid & 4) ? 16384 : 0);
  int rsub = lane >> 3;
  int gc = (lane & 7) ^ rsub;
  int gq = wid & 3;
#pragma unroll
  for (int m = 0; m < 2; ++m)
#pragma unroll
    for (int q = 0; q < 2; ++q) acc[m][q] = (f32x4){0.f, 0.f, 0.f, 0.f};
  float xa[2], xb[2];
#pragma unroll
  for (int s2 = 0; s2 < 8; ++s2) {
    int g = gq * 8 + s2;
    gload16(ap + (size_t)(g * 8 + rsub) * CD + gc * 8, ldsA + g * 512);
  }
#pragma unroll
  for (int ee = 0; ee < 2; ++ee) {
    int flat = ee * 512 + t;
    int c2 = flat >> 5, p = flat & 31;
    const float* src = Xn + (size_t)(2 * c2) * HW + j0 + p;
    xa[ee] = src[0];
    xb[ee] = src[HW];
  }
#pragma unroll
  for (int s = 0; s < 4; ++s) {
#pragma unroll
    for (int ee = 0; ee < 2; ++ee) {
      int flat = ee * 512 + t;
      int c2 = flat >> 5, p = flat & 31;
      int c = 2 * c2;
      int off = p * 64 + ((((c >> 3)) ^ (p & 7)) << 3) + (c & 7);
      unsigned short ha = f2bf(xa[ee]), hb = f2bf(xb[ee]);
      ushort2 hv; hv.x = ha; hv.y = hb;
      ushort2 lv; lv.x = f2bf(xa[ee] - bfhi(ha)); lv.y = f2bf(xb[ee] - bfhi(hb));
      *(ushort2*)(sm + 32768 + off) = hv;
      *(ushort2*)(sm + 34816 + off) = lv;
    }
    float xa2[2], xb2[2];
    if (s < 3) {
#pragma unroll
      for (int ee = 0; ee < 2; ++ee) {
        int flat = ee * 512 + t;
        int c2 = flat >> 5, p = flat & 31;
        const float* src = Xn + (size_t)((s + 1) * 64 + 2 * c2) * HW + j0 + p;
        xa2[ee] = src[0];
        xb2[ee] = src[HW];
      }
    }
    __syncthreads();
    mfma_body_kf(sm, acc);
    __syncthreads();
    if (s < 3) {
#pragma unroll
      for (int s2 = 0; s2 < 8; ++s2) {
        int g = gq * 8 + s2;
        gload16(ap + (size_t)(g * 8 + rsub) * CD + (s + 1) * 64 + gc * 8, ldsA + g * 512);
      }
#pragma unroll
      for (int ee = 0; ee < 2; ++ee) { xa[ee] = xa2[ee]; xb[ee] = xb2[ee]; }
    }
  }
}

// ---------- coalesced fp32 epilogue, 128x128 tile (kB gram) ----------
__device__ __forceinline__ void epi_store(f32x4 acc[4][2], float* smf, float* dst,
                                          int ld, const float* cvrow) {
  int t = threadIdx.x, lane = t & 63, wid = t >> 6;
  int wr = wid >> 2, wc = wid & 3;
#pragma unroll
  for (int m = 0; m < 4; ++m) {
    int rbase = wr * 64 + m * 16 + ((lane >> 4) << 2);
#pragma unroll
    for (int q = 0; q < 2; ++q) {
      int col = wc * 32 + q * 16 + (lane & 15);
#pragma unroll
      for (int e = 0; e < 4; ++e) {
        int row = rbase + e;
        smf[row * 128 + (col ^ ((row & 4) << 2))] = acc[m][q][e];
      }
    }
  }
  __syncthreads();
#pragma unroll
  for (int it = 0; it < 8; ++it) {
    int row = it * 16 + wid * 2 + (lane >> 5);
    int col = (lane & 31) * 4;
    float4 v = *(const float4*)&smf[row * 128 + (col ^ ((row & 4) << 2))];
    if (cvrow) {
      float cb = cvrow[row];
      v.x += cb; v.y += cb; v.z += cb; v.w += cb;
    }
    *(float4*)(dst + (size_t)row * ld + col) = v;
  }
}

// ---------- kF epilogue: 256 rows x 32 cols, stride-36 LDS, +cv ----------
__device__ __forceinline__ void epi_store256(f32x4 acc[2][2], float* smf, float* dst,
                                             const float* cvrow) {
  int t = threadIdx.x, lane = t & 63, wid = t >> 6;
#pragma unroll
  for (int m = 0; m < 2; ++m) {
#pragma unroll
    for (int q = 0; q < 2; ++q) {
      int col = q * 16 + (lane & 15);
#pragma unroll
      for (int e = 0; e < 4; ++e) {
        int row = wid * 32 + m * 16 + ((lane >> 4) << 2) + e;
        smf[row * 36 + col] = acc[m][q][e];
      }
    }
  }
  __syncthreads();
#pragma unroll
  for (int it = 0; it < 4; ++it) {
    int slot = it * 512 + t;
    int row = slot >> 3, col = (slot & 7) * 4;
    float4 v = *(const float4*)&smf[row * 36 + col];
    float cb = cvrow[row];
    v.x += cb; v.y += cb; v.z += cb; v.w += cb;
    *(float4*)(dst + (size_t)row * HW + col) = v;
  }
}

// ---------- kB: gram (384) + EF on-the-fly (8) + small vectors (13) ----------
__global__ __launch_bounds__(512) void kB(
    const float* __restrict__ X, float* __restrict__ Gp, float* __restrict__ psum2,
    const float* __restrict__ w0, const float* __restrict__ w1,
    const float* __restrict__ w2, const float* __restrict__ w3,
    const float* __restrict__ b0, const float* __restrict__ b1,
    const float* __restrict__ b2, unsigned short* __restrict__ Eh,
    unsigned short* __restrict__ El, float* __restrict__ Et,
    unsigned short* __restrict__ Fth, unsigned short* __restrict__ Ftl,
    float* __restrict__ Ff, float* __restrict__ vp, float* __restrict__ bpv,
    float* __restrict__ dlt, float* __restrict__ scal1) {
  __shared__ __align__(16) unsigned short sm[32768];
  int x = blockIdx.x, t = threadIdx.x;
  if (x < 384) {
    int tile = x % 3;  // 0: (0,0) diag, 1: (0,128), 2: (128,128) diag
    int z = x / 3;
    int n = z >> 5, ks = z & 31;
    const float* Xn = X + (size_t)n * CD * HW;
    f32x4 acc[4][2];
    if (tile == 1) {
      gram_core<false, 2>(Xn, 0, 128, ks * 128, sm, acc, nullptr);
      epi_store(acc, (float*)sm, Gp + ((size_t)ks * NB + n) * CC + 128, CD, nullptr);
    } else {
      int i0 = (tile == 2) ? 128 : 0;
      float* psRow = psum2 + ((size_t)n * KSG + ks) * 256 + i0;
      gram_core<true, 2>(Xn, i0, i0, ks * 128, sm, acc, psRow);
      epi_store(acc, (float*)sm,
                Gp + ((size_t)ks * NB + n) * CC + (size_t)i0 * CD + i0, CD, nullptr);
    }
  } else if (x < 392) {
    int e = x - 384;
    int zc = e >> 2, q = e & 3;
    int i0 = (q >> 1) * 128, j0 = (q & 1) * 128;
    f32x4 acc[4][2];
#pragma unroll
    for (int m = 0; m < 4; ++m)
#pragma unroll
      for (int qq = 0; qq < 2; ++qq) acc[m][qq] = (f32x4){0.f, 0.f, 0.f, 0.f};
    for (int s = 0; s < 4; ++s) {
      int k0 = s * 64;
      if (zc == 0) stage_rowA(w3, CD, i0, k0, sm);
      else stage_colT(w2, CD, i0, k0, sm);
      stage_colT(zc ? w1 : w0, CD, j0, k0, sm + 16384);
      __syncthreads();
      mfma_body<16384>(sm, acc);
      __syncthreads();
    }
    unsigned short* oh = zc ? Fth : Eh;
    unsigned short* ol = zc ? Ftl : El;
    float* tf = zc ? Ff : Et;
    int lane = t & 63, wid = t >> 6, wr = wid >> 2, wc = wid & 3;
#pragma unroll
    for (int m = 0; m < 4; ++m) {
      int row = i0 + wr * 64 + m * 16 + ((lane >> 4) << 2);
#pragma unroll
      for (int q2 = 0; q2 < 2; ++q2) {
        int col = j0 + wc * 32 + q2 * 16 + (lane & 15);
#pragma unroll
        for (int e2 = 0; e2 < 4; ++e2) {
          float v = acc[m][q2][e2];
          unsigned short hh = f2bf(v), ll = f2bf(v - bfhi(hh));
          oh[(size_t)(row + e2) * CD + col] = hh;
          ol[(size_t)(row + e2) * CD + col] = ll;
          tf[(size_t)col * CD + row + e2] = v;
        }
      }
    }
  } else {
    int task = x - 392;
    if (task < 8) {
      float* vin = (float*)sm;
      int seg = task & 3;
      const float* Wm = (task < 4) ? w1 : w2;
      const float* v = (task < 4) ? b2 : b1;
      float* dst = (task < 4) ? (vp + seg * CD) : (bpv + seg * CD);
      if (t < 64) vin[t] = v[seg * 64 + t];
      __syncthreads();
      if (t < 256) {
        float a = 0.f;
#pragma unroll 16
        for (int kk = 0; kk < 64; ++kk)
          a += Wm[(size_t)(seg * 64 + kk) * CD + t] * vin[kk];
        dst[t] = a;
      }
    } else if (task < 12) {
      int lane = t & 63, wv = t >> 6;
      float4 bvv = *(const float4*)(b0 + lane * 4);
#pragma unroll
      for (int i = 0; i < 8; ++i) {
        int o = (task - 8) * 64 + wv * 8 + i;
        float4 v = *(const float4*)(w3 + (size_t)o * CD + lane * 4);
        float a = v.x * bvv.x + v.y * bvv.y + v.z * bvv.z + v.w * bvv.w;
        a += __shfl_xor(a, 1);  a += __shfl_xor(a, 2);  a += __shfl_xor(a, 4);
        a += __shfl_xor(a, 8);  a += __shfl_xor(a, 16); a += __shfl_xor(a, 32);
        if (lane == 0) dlt[o] = a;
      }
    } else if (task == 12) {
      float* red = (float*)sm;
      if (t < 256) red[t] = b1[t] * b2[t];
      __syncthreads();
      for (int off = 128; off > 0; off >>= 1) {
        if (t < off) red[t] += red[t + off];
        __syncthreads();
      }
      if (t == 0) scal1[0] = red[0];
    }
  }
}

// ---------- kC: gram reduce (+mirror, +bf16 hi/lo) + sag (100 blocks) ----------
__global__ __launch_bounds__(512) void kC(
    const float* __restrict__ Gp, float* __restrict__ G,
    unsigned short* __restrict__ Gh, unsigned short* __restrict__ Gl,
    const float* __restrict__ psum2, const float* __restrict__ vp,
    const float* __restrict__ Ff, const float* __restrict__ Et,
    float* __restrict__ alp, float* __restrict__ gam, float* __restrict__ scal0) {
  __shared__ float smf[512];
  int b = blockIdx.x, t = threadIdx.x;
  if (b < 96) {
#pragma unroll
    for (int s = 0; s < 4; ++s) {
      int f = b * 2048 + s * 512 + t;
      int b2 = f >> 8, tt = f & 255;
      int quad = b2 >> 8, r = b2 & 255, n = r >> 6;
      int idx = (r & 63) * 256 + tt;
      int i = (idx >> 7) + ((quad == 2) ? 128 : 0);
      int j = (idx & 127) + ((quad >= 1) ? 128 : 0);
      float a = 0.f;
#pragma unroll 8
      for (int ks = 0; ks < KSG; ++ks)
        a += Gp[((size_t)ks * NB + n) * CC + (size_t)i * CD + j];
      size_t o = (size_t)n * CC + (size_t)i * CD + j;
      unsigned short hh = f2bf(a), ll = f2bf(a - bfhi(hh));
      G[o] = a; Gh[o] = hh; Gl[o] = ll;
      if (quad == 1) {
        size_t o2 = (size_t)n * CC + (size_t)j * CD + i;
        G[o2] = a; Gh[o2] = hh; Gl[o2] = ll;
      }
    }
  } else {
    int n = b - 96;
    float* ss = smf;
    float* red = ss + 256;
    float a = 0.f;
    if (t < 256) {
#pragma unroll 8
      for (int ks = 0; ks < KSG; ++ks) a += psum2[((size_t)n * KSG + ks) * 256 + t];
      ss[t] = a;
      red[t] = a * (vp[t] + vp[CD + t] + vp[2 * CD + t] + vp[3 * CD + t]);
    }
    __syncthreads();
    for (int off = 128; off > 0; off >>= 1) {
      if (t < off) red[t] += red[t + off];
      __syncthreads();
    }
    if (t == 0) scal0[n] = red[0];
    if (t < 256) {
      float al = 0.f, ga = 0.f;
#pragma unroll 16
      for (int k = 0; k < CD; ++k) {
        float sk = ss[k];
        al += Ff[(size_t)k * CD + t] * sk;
        ga += Et[(size_t)k * CD + t] * sk;
      }
      alp[n * CD + t] = al;
      gam[n * CD + t] = ga;
    }
  }
}

// ---------- kD1: Rm (16 blocks) + cv (4 blocks) ----------
__global__ __launch_bounds__(512) void kD1(
    const unsigned short* __restrict__ Eh, const unsigned short* __restrict__ El,
    const unsigned short* __restrict__ Gh, const unsigned short* __restrict__ Gl,
    unsigned short* __restrict__ Rh, unsigned short* __restrict__ Rl,
    const float* __restrict__ G, const float* __restrict__ Et,
    const float* __restrict__ vp, const float* __restrict__ dlt,
    const float* __restrict__ gam, const float* __restrict__ scal0,
    const float* __restrict__ scal1, const float* __restrict__ b3,
    float* __restrict__ cv) {
  __shared__ __align__(16) unsigned short sm[32768];
  int b = blockIdx.x, t = threadIdx.x;
  if (b < 16) {
    int n = b >> 2, i0 = ((b >> 1) & 1) * 128, j0 = (b & 1) * 128;
    f32x4 acc[4][2];
    mfma_nt_core(Eh, El, Gh + (size_t)n * CC, Gl + (size_t)n * CC, i0, j0, sm, acc);
    int lane = t & 63, wid = t >> 6, wr = wid >> 2, wc = wid & 3;
#pragma unroll
    for (int m = 0; m < 4; ++m) {
      int row = i0 + wr * 64 + m * 16 + ((lane >> 4) << 2);
#pragma unroll
      for (int q = 0; q < 2; ++q) {
        int col = j0 + wc * 32 + q * 16 + (lane & 15);
#pragma unroll
        for (int e = 0; e < 4; ++e) {
          float v = acc[m][q][e];
          unsigned short hh = f2bf(v), ll = f2bf(v - bfhi(hh));
          Rh[(size_t)n * CC + (size_t)(row + e) * CD + col] = hh;
          Rl[(size_t)n * CC + (size_t)(row + e) * CD + col] = ll;
        }
      }
    }
  } else {
    int n = b - 16;
    float* vsh = (float*)sm;
    float* g1 = vsh + CD;
    if (t < CD) vsh[t] = vp[t] + vp[CD + t] + vp[2 * CD + t] + vp[3 * CD + t];
    __syncthreads();
    if (t < CD) {
      const float* Gn = G + (size_t)n * CC;
      float a = 0.f;
#pragma unroll 8
      for (int k = 0; k < CD; ++k) a += Gn[(size_t)k * CD + t] * vsh[k];
      g1[t] = a;
    }
    __syncthreads();
    if (t < CD) {
      float c2 = 0.f;
#pragma unroll 8
      for (int k = 0; k < CD; ++k) c2 += Et[(size_t)k * CD + t] * g1[k];
      cv[n * CD + t] = (c2 + scal0[n] * dlt[t] +
                        scal1[0] * (gam[n * CD + t] + (float)HW * dlt[t])) *
                           (1.0f / HW) +
                       b3[t];
    }
  }
}

// ---------- kD2: Atm (16 blocks) ----------
__global__ __launch_bounds__(512) void kD2(
    const unsigned short* __restrict__ Rh, const unsigned short* __restrict__ Rl,
    const unsigned short* __restrict__ Fth, const unsigned short* __restrict__ Ftl,
    unsigned short* __restrict__ Athi, unsigned short* __restrict__ Atlo,
    const float* __restrict__ dlt, const float* __restrict__ alp,
    const float* __restrict__ gam, const float* __restrict__ bpv) {
  __shared__ __align__(16) unsigned short sm[32768];
  int b = blockIdx.x, t = threadIdx.x;
  int n = b >> 2, i0 = ((b >> 1) & 1) * 128, j0 = (b & 1) * 128;
  f32x4 acc[4][2];
  mfma_nt_core(Rh + (size_t)n * CC, Rl + (size_t)n * CC, Fth, Ftl, i0, j0, sm, acc);
  int lane = t & 63, wid = t >> 6, wr = wid >> 2, wc = wid & 3;
#pragma unroll
  for (int m = 0; m < 4; ++m) {
    int row = i0 + wr * 64 + m * 16 + ((lane >> 4) << 2);
#pragma unroll
    for (int q = 0; q < 2; ++q) {
      int col = j0 + wc * 32 + q * 16 + (lane & 15);
      float bj = bpv[col] + bpv[CD + col] + bpv[2 * CD + col] + bpv[3 * CD + col];
      float aj = alp[n * CD + col];
#pragma unroll
      for (int e = 0; e < 4; ++e) {
        float di = dlt[row + e], gi = gam[n * CD + row + e];
        float v = (acc[m][q][e] + di * aj + gi * bj) * (1.0f / HW) + di * bj;
        unsigned short hh = f2bf(v), ll = f2bf(v - bfhi(hh));
        Athi[(size_t)n * CC + (size_t)(row + e) * CD + col] = hh;
        Atlo[(size_t)n * CC + (size_t)(row + e) * CD + col] = ll;
      }
    }
  }
}

// ---------- kF: out = At x X, 256-row x 32-col panels (X read once) + cv ----------
__global__ __launch_bounds__(512) void kF(const unsigned short* __restrict__ Athi,
                                          const unsigned short* __restrict__ Atlo,
                                          const float* __restrict__ X,
                                          const float* __restrict__ cv,
                                          float* __restrict__ out) {
  int n = blockIdx.y;
  int j0 = blockIdx.x * 32;
  __shared__ __align__(16) unsigned short sm[36864];  // 72 KB: Ah|Al|Bh|Bl
  f32x4 acc[2][2];
  final_core256(Athi + (size_t)n * CC, Atlo + (size_t)n * CC, X + (size_t)n * CD * HW,
                j0, sm, acc);
  epi_store256(acc, (float*)sm, out + (size_t)n * CD * HW + j0, cv + n * CD);
}

extern "C" void kernel_launch(void* const* d_in, const int* in_sizes, int n_in,
                              void* d_out, int out_size, void* d_ws, size_t ws_size,
                              hipStream_t stream) {
  const float* X = (const float*)d_in[0];
  const float* w0 = (const float*)d_in[1];
  const float* b0 = (const float*)d_in[2];
  const float* w1 = (const float*)d_in[3];
  const float* b1 = (const float*)d_in[4];
  const float* w2 = (const float*)d_in[5];
  const float* b2 = (const float*)d_in[6];
  const float* w3 = (const float*)d_in[7];
  const float* b3 = (const float*)d_in[8];
  float* out = (float*)d_out;
  float* ws = (float*)d_ws;

  float* cv    = ws;
  float* alp   = ws + 1024;
  float* gam   = ws + 2048;
  float* dlt   = ws + 3072;
  float* vp    = ws + 4096;
  float* bpv   = ws + 5120;
  float* scal0 = ws + 6144;
  float* scal1 = ws + 6176;
  float* psum2 = ws + 8192;                    // NB*KSG*256 = 32768
  float* Et    = psum2 + 32768;
  float* Ff    = Et + CC;
  float* G     = Ff + CC;                      // NB*CC
  float* Gp    = G + (size_t)NB * CC;          // KSG*NB*CC
  unsigned short* Eh   = (unsigned short*)(Gp + (size_t)KSG * NB * CC);
  unsigned short* El   = Eh + CC;
  unsigned short* Fth  = El + CC;
  unsigned short* Ftl  = Fth + CC;
  unsigned short* Gh   = Ftl + CC;
  unsigned short* Gl   = Gh + (size_t)NB * CC;
  unsigned short* Rh   = Gl + (size_t)NB * CC;
  unsigned short* Rl   = Rh + (size_t)NB * CC;
  unsigned short* Athi = Rl + (size_t)NB * CC;
  unsigned short* Atlo = Athi + (size_t)NB * CC;

  kB<<<dim3(405), 512, 0, stream>>>(X, Gp, psum2, w0, w1, w2, w3, b0, b1, b2, Eh, El,
                                    Et, Fth, Ftl, Ff, vp, bpv, dlt, scal1);
  kC<<<dim3(100), 512, 0, stream>>>(Gp, G, Gh, Gl, psum2, vp, Ff, Et, alp, gam, scal0);
  kD1<<<dim3(20), 512, 0, stream>>>(Eh, El, Gh, Gl, Rh, Rl, G, Et, vp, dlt, gam, scal0,
                                    scal1, b3, cv);
  kD2<<<dim3(16), 512, 0, stream>>>(Rh, Rl, Fth, Ftl, Athi, Atlo, dlt, alp, gam, bpv);
  kF<<<dim3(HW / 32, NB), 512, 0, stream>>>(Athi, Atlo, X, cv, out);
}

// Round 12
// 82.597 us; speedup vs baseline: 1.0472x; 1.0472x over previous
//
#include <hip/hip_runtime.h>

#define NB 4
#define CD 256
#define HW 4096
#define KSG 16
#define CC (CD * CD)

typedef __attribute__((ext_vector_type(8))) short bf16x8;
typedef __attribute__((ext_vector_type(4))) float f32x4;

__device__ inline unsigned short f2bf(float x) {
  unsigned int u = __float_as_uint(x);
  unsigned int r = (u + 0x7FFFu + ((u >> 16) & 1u)) >> 16;
  return (unsigned short)r;
}
__device__ inline float bfhi(unsigned short h) {
  return __uint_as_float(((unsigned int)h) << 16);
}
__device__ __forceinline__ void gload16(const unsigned short* g, unsigned short* l) {
  __builtin_amdgcn_global_load_lds((const __attribute__((address_space(1))) void*)g,
                                   (__attribute__((address_space(3))) void*)l, 16, 0, 0);
}

// ---------- sleep-backoff grid barrier: relaxed poll (no invalidate storm) ----------
__device__ __forceinline__ void gridbar(unsigned int* ctr, unsigned int target) {
  __syncthreads();
  if (threadIdx.x == 0) {
    __hip_atomic_fetch_add(ctr, 1u, __ATOMIC_RELEASE, __HIP_MEMORY_SCOPE_AGENT);
    while (__hip_atomic_load(ctr, __ATOMIC_RELAXED, __HIP_MEMORY_SCOPE_AGENT) < target)
      __builtin_amdgcn_s_sleep(8);
    (void)__hip_atomic_load(ctr, __ATOMIC_ACQUIRE, __HIP_MEMORY_SCOPE_AGENT);
  }
  __syncthreads();
}

// ---------- MFMA body (128-row A, 128-col B): A at sm[0]/sm[8192], B at sm[BOFF]/+8192 ----------
template <int BOFF>
__device__ __forceinline__ void mfma_body(const unsigned short* sm, f32x4 acc[4][2]) {
  int t = threadIdx.x, lane = t & 63, wid = t >> 6;
  int wr = wid >> 2, wc = wid & 3;
  int lrow = lane & 15, lkb = lane >> 4;
#pragma unroll
  for (int ks2 = 0; ks2 < 2; ++ks2) {
    bf16x8 ah[4], al[4], bh[2], bl[2];
#pragma unroll
    for (int m = 0; m < 4; ++m) {
      int r = wr * 64 + m * 16 + lrow;
      int sw = ((ks2 * 4 + lkb) ^ (r & 7)) * 8;
      ah[m] = *(const bf16x8*)(sm + r * 64 + sw);
      al[m] = *(const bf16x8*)(sm + 8192 + r * 64 + sw);
    }
#pragma unroll
    for (int q = 0; q < 2; ++q) {
      int r = wc * 32 + q * 16 + lrow;
      int sw = ((ks2 * 4 + lkb) ^ (r & 7)) * 8;
      bh[q] = *(const bf16x8*)(sm + BOFF + r * 64 + sw);
      bl[q] = *(const bf16x8*)(sm + BOFF + 8192 + r * 64 + sw);
    }
#pragma unroll
    for (int m = 0; m < 4; ++m)
#pragma unroll
      for (int q = 0; q < 2; ++q) {
        acc[m][q] = __builtin_amdgcn_mfma_f32_16x16x32_bf16(ah[m], bh[q], acc[m][q], 0, 0, 0);
        acc[m][q] = __builtin_amdgcn_mfma_f32_16x16x32_bf16(ah[m], bl[q], acc[m][q], 0, 0, 0);
        acc[m][q] = __builtin_amdgcn_mfma_f32_16x16x32_bf16(al[m], bh[q], acc[m][q], 0, 0, 0);
      }
  }
}

// ---------- bf16-operand NT core (gload16 staging) ----------
__device__ __forceinline__ void mfma_nt_core(
    const unsigned short* __restrict__ pH, const unsigned short* __restrict__ pL,
    const unsigned short* __restrict__ qH, const unsigned short* __restrict__ qL,
    int i0, int j0, unsigned short* sm, f32x4 acc[4][2]) {
  int t = threadIdx.x;
  int lane = t & 63, wid = t >> 6;
  int tsel = wid >> 1;
  int gbase = (wid & 1) * 8;
  const unsigned short* bp2 = (tsel == 0) ? pH : (tsel == 1) ? pL : (tsel == 2) ? qH : qL;
  int tb = (tsel < 2) ? i0 : j0;
  int rsub = lane >> 3;
  int gc = (lane & 7) ^ rsub;
  unsigned short* ldsT = sm + tsel * 8192;
#pragma unroll
  for (int m = 0; m < 4; ++m)
#pragma unroll
    for (int q = 0; q < 2; ++q) acc[m][q] = (f32x4){0.f, 0.f, 0.f, 0.f};
  for (int k0 = 0; k0 < 256; k0 += 64) {
#pragma unroll
    for (int s = 0; s < 8; ++s) {
      int g = gbase + s;
      gload16(bp2 + (size_t)(tb + g * 8 + rsub) * CD + k0 + gc * 8, ldsT + g * 512);
    }
    __syncthreads();
    mfma_body<16384>(sm, acc);
    __syncthreads();
  }
}

// ---------- gram core: operands from X fp32, reg-prefetch; DIAG stages A only ----------
template <bool DIAG, int NSTEP>
__device__ __forceinline__ void gram_core(const float* __restrict__ Xn, int i0, int j0,
                                          int kBegin, unsigned short* sm,
                                          f32x4 acc[4][2], float* __restrict__ psumRow) {
  int t = threadIdx.x;
  int r16 = t >> 4, k4 = (t & 15) * 4;
  int kg = k4 >> 3, kr = k4 & 7;
#pragma unroll
  for (int m = 0; m < 4; ++m)
#pragma unroll
    for (int q = 0; q < 2; ++q) acc[m][q] = (f32x4){0.f, 0.f, 0.f, 0.f};
  float ps[4] = {0.f, 0.f, 0.f, 0.f};
  float4 av[4], bv[4];
#pragma unroll
  for (int j = 0; j < 4; ++j) {
    av[j] = *(const float4*)(Xn + (size_t)(i0 + j * 32 + r16) * HW + kBegin + k4);
    if (!DIAG)
      bv[j] = *(const float4*)(Xn + (size_t)(j0 + j * 32 + r16) * HW + kBegin + k4);
  }
#pragma unroll
  for (int s = 0; s < NSTEP; ++s) {
    float4 av2[4], bv2[4];
    if (s < NSTEP - 1) {
#pragma unroll
      for (int j = 0; j < 4; ++j) {
        av2[j] = *(const float4*)(Xn + (size_t)(i0 + j * 32 + r16) * HW + kBegin +
                                  (s + 1) * 64 + k4);
        if (!DIAG)
          bv2[j] = *(const float4*)(Xn + (size_t)(j0 + j * 32 + r16) * HW + kBegin +
                                    (s + 1) * 64 + k4);
      }
    }
#pragma unroll
    for (int j = 0; j < 4; ++j) {
      int r = j * 32 + r16;
      int off = r * 64 + ((kg ^ (r & 7)) << 3) + kr;
      ushort4 h, l;
      h.x = f2bf(av[j].x); l.x = f2bf(av[j].x - bfhi(h.x));
      h.y = f2bf(av[j].y); l.y = f2bf(av[j].y - bfhi(h.y));
      h.z = f2bf(av[j].z); l.z = f2bf(av[j].z - bfhi(h.z));
      h.w = f2bf(av[j].w); l.w = f2bf(av[j].w - bfhi(h.w));
      *(ushort4*)(sm + off) = h;
      *(ushort4*)(sm + 8192 + off) = l;
      ps[j] += av[j].x + av[j].y + av[j].z + av[j].w;
      if (!DIAG) {
        h.x = f2bf(bv[j].x); l.x = f2bf(bv[j].x - bfhi(h.x));
        h.y = f2bf(bv[j].y); l.y = f2bf(bv[j].y - bfhi(h.y));
        h.z = f2bf(bv[j].z); l.z = f2bf(bv[j].z - bfhi(h.z));
        h.w = f2bf(bv[j].w); l.w = f2bf(bv[j].w - bfhi(h.w));
        *(ushort4*)(sm + 16384 + off) = h;
        *(ushort4*)(sm + 24576 + off) = l;
      }
    }
    __syncthreads();
    mfma_body<DIAG ? 0 : 16384>(sm, acc);
    __syncthreads();
    if (s < NSTEP - 1) {
#pragma unroll
      for (int j = 0; j < 4; ++j) {
        av[j] = av2[j];
        if (!DIAG) bv[j] = bv2[j];
      }
    }
  }
  if (psumRow) {
#pragma unroll
    for (int j = 0; j < 4; ++j) {
      float v = ps[j];
      v += __shfl_xor(v, 1); v += __shfl_xor(v, 2);
      v += __shfl_xor(v, 4); v += __shfl_xor(v, 8);
      if ((t & 15) == 0) psumRow[j * 32 + r16] = v;
    }
  }
}

// ---------- ROW-stage: LDS[r][k] = W[r0+r][k0+k] (hi/lo) ----------
__device__ __forceinline__ void stage_rowA(const float* __restrict__ W, int ld, int r0,
                                           int k0, unsigned short* dst) {
  int t = threadIdx.x;
  int r16 = t >> 4, k4 = (t & 15) * 4;
  int kg = k4 >> 3, kr = k4 & 7;
#pragma unroll
  for (int j = 0; j < 4; ++j) {
    int r = j * 32 + r16;
    float4 v = *(const float4*)(W + (size_t)(r0 + r) * ld + k0 + k4);
    int off = r * 64 + ((kg ^ (r & 7)) << 3) + kr;
    ushort4 h, l;
    h.x = f2bf(v.x); l.x = f2bf(v.x - bfhi(h.x));
    h.y = f2bf(v.y); l.y = f2bf(v.y - bfhi(h.y));
    h.z = f2bf(v.z); l.z = f2bf(v.z - bfhi(h.z));
    h.w = f2bf(v.w); l.w = f2bf(v.w - bfhi(h.w));
    *(ushort4*)(dst + off) = h;
    *(ushort4*)(dst + 8192 + off) = l;
  }
}

// ---------- COL-stage (transpose): LDS[c][k] = W[k0+k][c0+c] (hi/lo), 128 cols ----------
__device__ __forceinline__ void stage_colT(const float* __restrict__ W, int ld, int c0,
                                           int k0, unsigned short* dst) {
  int t = threadIdx.x;
#pragma unroll
  for (int ee = 0; ee < 8; ++ee) {
    int flat = ee * 512 + t;
    int c2 = flat >> 7, p = flat & 127;
    const float* src = W + (size_t)(k0 + 2 * c2) * ld + c0 + p;
    float xa = src[0], xb = src[ld];
    int c = 2 * c2;
    int off = p * 64 + ((((c >> 3)) ^ (p & 7)) << 3) + (c & 7);
    unsigned short ha = f2bf(xa), hb = f2bf(xb);
    ushort2 hv; hv.x = ha; hv.y = hb;
    ushort2 lv; lv.x = f2bf(xa - bfhi(ha)); lv.y = f2bf(xb - bfhi(hb));
    *(ushort2*)(dst + off) = hv;
    *(ushort2*)(dst + 8192 + off) = lv;
  }
}

// ---------- final core: A = At bf16 via gload16; B = X fp32 transpose-staged w/ prefetch ----------
__device__ __forceinline__ void final_core(const unsigned short* __restrict__ aH,
                                           const unsigned short* __restrict__ aL,
                                           const float* __restrict__ Xn, int i0, int j0,
                                           unsigned short* sm, f32x4 acc[4][2]) {
  int t = threadIdx.x, lane = t & 63, wid = t >> 6;
  const unsigned short* ap = (wid & 4) ? aL : aH;
  unsigned short* ldsA = sm + ((wid & 4) ? 8192 : 0);
  int rsub = lane >> 3;
  int gc = (lane & 7) ^ rsub;
  int gq = wid & 3;
#pragma unroll
  for (int m = 0; m < 4; ++m)
#pragma unroll
    for (int q = 0; q < 2; ++q) acc[m][q] = (f32x4){0.f, 0.f, 0.f, 0.f};
  float xa[8], xb[8];
#pragma unroll
  for (int s2 = 0; s2 < 4; ++s2) {
    int g = gq * 4 + s2;
    gload16(ap + (size_t)(i0 + g * 8 + rsub) * CD + gc * 8, ldsA + g * 512);
  }
#pragma unroll
  for (int ee = 0; ee < 8; ++ee) {
    int flat = ee * 512 + t;
    int c2 = flat >> 7, p = flat & 127;
    const float* src = Xn + (size_t)(2 * c2) * HW + j0 + p;
    xa[ee] = src[0];
    xb[ee] = src[HW];
  }
#pragma unroll
  for (int s = 0; s < 4; ++s) {
#pragma unroll
    for (int ee = 0; ee < 8; ++ee) {
      int flat = ee * 512 + t;
      int c2 = flat >> 7, p = flat & 127;
      int c = 2 * c2;
      int off = p * 64 + ((((c >> 3)) ^ (p & 7)) << 3) + (c & 7);
      unsigned short ha = f2bf(xa[ee]), hb = f2bf(xb[ee]);
      ushort2 hv; hv.x = ha; hv.y = hb;
      ushort2 lv; lv.x = f2bf(xa[ee] - bfhi(ha)); lv.y = f2bf(xb[ee] - bfhi(hb));
      *(ushort2*)(sm + 16384 + off) = hv;
      *(ushort2*)(sm + 24576 + off) = lv;
    }
    float xa2[8], xb2[8];
    if (s < 3) {
#pragma unroll
      for (int ee = 0; ee < 8; ++ee) {
        int flat = ee * 512 + t;
        int c2 = flat >> 7, p = flat & 127;
        const float* src = Xn + (size_t)((s + 1) * 64 + 2 * c2) * HW + j0 + p;
        xa2[ee] = src[0];
        xb2[ee] = src[HW];
      }
    }
    __syncthreads();
    mfma_body<16384>(sm, acc);
    __syncthreads();
    if (s < 3) {
#pragma unroll
      for (int s2 = 0; s2 < 4; ++s2) {
        int g = gq * 4 + s2;
        gload16(ap + (size_t)(i0 + g * 8 + rsub) * CD + (s + 1) * 64 + gc * 8,
                ldsA + g * 512);
      }
#pragma unroll
      for (int ee = 0; ee < 8; ++ee) { xa[ee] = xa2[ee]; xb[ee] = xb2[ee]; }
    }
  }
}

// ---------- coalesced fp32 epilogue ----------
__device__ __forceinline__ void epi_store(f32x4 acc[4][2], float* smf, float* dst,
                                          int ld, const float* cvrow) {
  int t = threadIdx.x, lane = t & 63, wid = t >> 6;
  int wr = wid >> 2, wc = wid & 3;
#pragma unroll
  for (int m = 0; m < 4; ++m) {
    int rbase = wr * 64 + m * 16 + ((lane >> 4) << 2);
#pragma unroll
    for (int q = 0; q < 2; ++q) {
      int col = wc * 32 + q * 16 + (lane & 15);
#pragma unroll
      for (int e = 0; e < 4; ++e) {
        int row = rbase + e;
        smf[row * 128 + (col ^ ((row & 4) << 2))] = acc[m][q][e];
      }
    }
  }
  __syncthreads();
#pragma unroll
  for (int it = 0; it < 8; ++it) {
    int row = it * 16 + wid * 2 + (lane >> 5);
    int col = (lane & 31) * 4;
    float4 v = *(const float4*)&smf[row * 128 + (col ^ ((row & 4) << 2))];
    if (cvrow) {
      float cb = cvrow[row];
      v.x += cb; v.y += cb; v.z += cb; v.w += cb;
    }
    *(float4*)(dst + (size_t)row * ld + col) = v;
  }
}

// ---------- kB: gram (192) + EF on-the-fly (8) + small vectors (13) ----------
__global__ __launch_bounds__(512) void kB(
    const float* __restrict__ X, float* __restrict__ Gp, float* __restrict__ psum2,
    const float* __restrict__ w0, const float* __restrict__ w1,
    const float* __restrict__ w2, const float* __restrict__ w3,
    const float* __restrict__ b0, const float* __restrict__ b1,
    const float* __restrict__ b2, unsigned short* __restrict__ Eh,
    unsigned short* __restrict__ El, float* __restrict__ Et,
    unsigned short* __restrict__ Fth, unsigned short* __restrict__ Ftl,
    float* __restrict__ Ff, float* __restrict__ vp, float* __restrict__ bpv,
    float* __restrict__ dlt, float* __restrict__ scal1,
    unsigned int* __restrict__ barctr) {
  __shared__ __align__(16) unsigned short sm[32768];
  int x = blockIdx.x, t = threadIdx.x;
  if (x < 192) {
    int tile = x % 3;  // 0: (0,0) diag, 1: (0,128), 2: (128,128) diag
    int z = x / 3;
    int n = z >> 4, ks = z & 15;
    const float* Xn = X + (size_t)n * CD * HW;
    f32x4 acc[4][2];
    if (tile == 1) {
      gram_core<false, 4>(Xn, 0, 128, ks * 256, sm, acc, nullptr);
      epi_store(acc, (float*)sm, Gp + ((size_t)ks * NB + n) * CC + 128, CD, nullptr);
    } else {
      int i0 = (tile == 2) ? 128 : 0;
      float* psRow = psum2 + ((size_t)n * KSG + ks) * 256 + i0;
      gram_core<true, 4>(Xn, i0, i0, ks * 256, sm, acc, psRow);
      epi_store(acc, (float*)sm,
                Gp + ((size_t)ks * NB + n) * CC + (size_t)i0 * CD + i0, CD, nullptr);
    }
  } else if (x < 200) {
    int e = x - 192;
    int zc = e >> 2, q = e & 3;
    int i0 = (q >> 1) * 128, j0 = (q & 1) * 128;
    f32x4 acc[4][2];
#pragma unroll
    for (int m = 0; m < 4; ++m)
#pragma unroll
      for (int qq = 0; qq < 2; ++qq) acc[m][qq] = (f32x4){0.f, 0.f, 0.f, 0.f};
    for (int s = 0; s < 4; ++s) {
      int k0 = s * 64;
      if (zc == 0) stage_rowA(w3, CD, i0, k0, sm);
      else stage_colT(w2, CD, i0, k0, sm);
      stage_colT(zc ? w1 : w0, CD, j0, k0, sm + 16384);
      __syncthreads();
      mfma_body<16384>(sm, acc);
      __syncthreads();
    }
    unsigned short* oh = zc ? Fth : Eh;
    unsigned short* ol = zc ? Ftl : El;
    float* tf = zc ? Ff : Et;
    int lane = t & 63, wid = t >> 6, wr = wid >> 2, wc = wid & 3;
#pragma unroll
    for (int m = 0; m < 4; ++m) {
      int row = i0 + wr * 64 + m * 16 + ((lane >> 4) << 2);
#pragma unroll
      for (int q2 = 0; q2 < 2; ++q2) {
        int col = j0 + wc * 32 + q2 * 16 + (lane & 15);
#pragma unroll
        for (int e2 = 0; e2 < 4; ++e2) {
          float v = acc[m][q2][e2];
          unsigned short hh = f2bf(v), ll = f2bf(v - bfhi(hh));
          oh[(size_t)(row + e2) * CD + col] = hh;
          ol[(size_t)(row + e2) * CD + col] = ll;
          tf[(size_t)col * CD + row + e2] = v;
        }
      }
    }
  } else {
    int task = x - 200;
    if (task == 12 && t == 0) { barctr[0] = 0u; barctr[1] = 0u; }
    if (task < 8) {
      float* vin = (float*)sm;
      int seg = task & 3;
      const float* Wm = (task < 4) ? w1 : w2;
      const float* v = (task < 4) ? b2 : b1;
      float* dst = (task < 4) ? (vp + seg * CD) : (bpv + seg * CD);
      if (t < 64) vin[t] = v[seg * 64 + t];
      __syncthreads();
      if (t < 256) {
        float a = 0.f;
#pragma unroll 16
        for (int kk = 0; kk < 64; ++kk)
          a += Wm[(size_t)(seg * 64 + kk) * CD + t] * vin[kk];
        dst[t] = a;
      }
    } else if (task < 12) {
      int lane = t & 63, wv = t >> 6;
      float4 bvv = *(const float4*)(b0 + lane * 4);
#pragma unroll
      for (int i = 0; i < 8; ++i) {
        int o = (task - 8) * 64 + wv * 8 + i;
        float4 v = *(const float4*)(w3 + (size_t)o * CD + lane * 4);
        float a = v.x * bvv.x + v.y * bvv.y + v.z * bvv.z + v.w * bvv.w;
        a += __shfl_xor(a, 1);  a += __shfl_xor(a, 2);  a += __shfl_xor(a, 4);
        a += __shfl_xor(a, 8);  a += __shfl_xor(a, 16); a += __shfl_xor(a, 32);
        if (lane == 0) dlt[o] = a;
      }
    } else if (task == 12) {
      float* red = (float*)sm;
      if (t < 256) red[t] = b1[t] * b2[t];
      __syncthreads();
      for (int off = 128; off > 0; off >>= 1) {
        if (t < off) red[t] += red[t + off];
        __syncthreads();
      }
      if (t == 0) scal1[0] = red[0];
    }
  }
}

// ---------- kCD: [reduce+sag] | gridbar | [Rm + cv] | gridbar | [Atm]  (100 blocks) ----------
__global__ __launch_bounds__(512) void kCD(
    const float* __restrict__ Gp, float* __restrict__ G,
    unsigned short* __restrict__ Gh, unsigned short* __restrict__ Gl,
    const float* __restrict__ psum2, const float* __restrict__ vp,
    const float* __restrict__ Ff, const float* __restrict__ Et,
    float* __restrict__ alp, float* __restrict__ gam, float* __restrict__ scal0,
    const unsigned short* __restrict__ Eh, const unsigned short* __restrict__ El,
    unsigned short* __restrict__ Rh, unsigned short* __restrict__ Rl,
    const float* __restrict__ dlt, const float* __restrict__ scal1,
    const float* __restrict__ b3, float* __restrict__ cv,
    const unsigned short* __restrict__ Fth, const unsigned short* __restrict__ Ftl,
    unsigned short* __restrict__ Athi, unsigned short* __restrict__ Atlo,
    const float* __restrict__ bpv, unsigned int* __restrict__ barctr) {
  __shared__ __align__(16) unsigned short sm[32768];
  int b = blockIdx.x, t = threadIdx.x;
  // ---- phase 1: Gp reduce (+mirror, +bf16 hi/lo) and sag ----
  if (b < 96) {
#pragma unroll
    for (int s = 0; s < 4; ++s) {
      int f = b * 2048 + s * 512 + t;
      int b2 = f >> 8, tt = f & 255;
      int quad = b2 >> 8, r = b2 & 255, n = r >> 6;
      int idx = (r & 63) * 256 + tt;
      int i = (idx >> 7) + ((quad == 2) ? 128 : 0);
      int j = (idx & 127) + ((quad >= 1) ? 128 : 0);
      float a = 0.f;
#pragma unroll
      for (int ks = 0; ks < KSG; ++ks)
        a += Gp[((size_t)ks * NB + n) * CC + (size_t)i * CD + j];
      size_t o = (size_t)n * CC + (size_t)i * CD + j;
      unsigned short hh = f2bf(a), ll = f2bf(a - bfhi(hh));
      G[o] = a; Gh[o] = hh; Gl[o] = ll;
      if (quad == 1) {
        size_t o2 = (size_t)n * CC + (size_t)j * CD + i;
        G[o2] = a; Gh[o2] = hh; Gl[o2] = ll;
      }
    }
  } else {
    int n = b - 96;
    float* ss = (float*)sm;
    float* red = ss + 256;
    float a = 0.f;
    if (t < 256) {
#pragma unroll
      for (int ks = 0; ks < KSG; ++ks) a += psum2[((size_t)n * KSG + ks) * 256 + t];
      ss[t] = a;
      red[t] = a * (vp[t] + vp[CD + t] + vp[2 * CD + t] + vp[3 * CD + t]);
    }
    __syncthreads();
    for (int off = 128; off > 0; off >>= 1) {
      if (t < off) red[t] += red[t + off];
      __syncthreads();
    }
    if (t == 0) scal0[n] = red[0];
    if (t < 256) {
      float al = 0.f, ga = 0.f;
#pragma unroll 16
      for (int k = 0; k < CD; ++k) {
        float sk = ss[k];
        al += Ff[(size_t)k * CD + t] * sk;
        ga += Et[(size_t)k * CD + t] * sk;
      }
      alp[n * CD + t] = al;
      gam[n * CD + t] = ga;
    }
  }
  gridbar(&barctr[0], 100u);
  // ---- phase 2: Rm (blocks 0-15) + cv (blocks 16-19) ----
  if (b < 16) {
    int n = b >> 2, i0 = ((b >> 1) & 1) * 128, j0 = (b & 1) * 128;
    f32x4 acc[4][2];
    mfma_nt_core(Eh, El, Gh + (size_t)n * CC, Gl + (size_t)n * CC, i0, j0, sm, acc);
    int lane = t & 63, wid = t >> 6, wr = wid >> 2, wc = wid & 3;
#pragma unroll
    for (int m = 0; m < 4; ++m) {
      int row = i0 + wr * 64 + m * 16 + ((lane >> 4) << 2);
#pragma unroll
      for (int q = 0; q < 2; ++q) {
        int col = j0 + wc * 32 + q * 16 + (lane & 15);
#pragma unroll
        for (int e = 0; e < 4; ++e) {
          float v = acc[m][q][e];
          unsigned short hh = f2bf(v), ll = f2bf(v - bfhi(hh));
          Rh[(size_t)n * CC + (size_t)(row + e) * CD + col] = hh;
          Rl[(size_t)n * CC + (size_t)(row + e) * CD + col] = ll;
        }
      }
    }
  } else if (b < 20) {
    int n = b - 16;
    float* vsh = (float*)sm;
    float* g1 = vsh + CD;
    if (t < CD) vsh[t] = vp[t] + vp[CD + t] + vp[2 * CD + t] + vp[3 * CD + t];
    __syncthreads();
    if (t < CD) {
      const float* Gn = G + (size_t)n * CC;
      float a = 0.f;
#pragma unroll 8
      for (int k = 0; k < CD; ++k) a += Gn[(size_t)k * CD + t] * vsh[k];
      g1[t] = a;
    }
    __syncthreads();
    if (t < CD) {
      float c2 = 0.f;
#pragma unroll 8
      for (int k = 0; k < CD; ++k) c2 += Et[(size_t)k * CD + t] * g1[k];
      cv[n * CD + t] = (c2 + scal0[n] * dlt[t] +
                        scal1[0] * (gam[n * CD + t] + (float)HW * dlt[t])) *
                           (1.0f / HW) +
                       b3[t];
    }
  }
  gridbar(&barctr[1], 100u);
  // ---- phase 3: Atm (blocks 0-15) ----
  if (b < 16) {
    int n = b >> 2, i0 = ((b >> 1) & 1) * 128, j0 = (b & 1) * 128;
    f32x4 acc[4][2];
    mfma_nt_core(Rh + (size_t)n * CC, Rl + (size_t)n * CC, Fth, Ftl, i0, j0, sm, acc);
    int lane = t & 63, wid = t >> 6, wr = wid >> 2, wc = wid & 3;
#pragma unroll
    for (int m = 0; m < 4; ++m) {
      int row = i0 + wr * 64 + m * 16 + ((lane >> 4) << 2);
#pragma unroll
      for (int q = 0; q < 2; ++q) {
        int col = j0 + wc * 32 + q * 16 + (lane & 15);
        float bj = bpv[col] + bpv[CD + col] + bpv[2 * CD + col] + bpv[3 * CD + col];
        float aj = alp[n * CD + col];
#pragma unroll
        for (int e = 0; e < 4; ++e) {
          float di = dlt[row + e], gi = gam[n * CD + row + e];
          float v = (acc[m][q][e] + di * aj + gi * bj) * (1.0f / HW) + di * bj;
          unsigned short hh = f2bf(v), ll = f2bf(v - bfhi(hh));
          Athi[(size_t)n * CC + (size_t)(row + e) * CD + col] = hh;
          Atlo[(size_t)n * CC + (size_t)(row + e) * CD + col] = ll;
        }
      }
    }
  }
}

// ---------- kF: out = At x X (B transposed+split on the fly, prefetched) + cv ----------
__global__ __launch_bounds__(512) void kF(const unsigned short* __restrict__ Athi,
                                          const unsigned short* __restrict__ Atlo,
                                          const float* __restrict__ X,
                                          const float* __restrict__ cv,
                                          float* __restrict__ out) {
  int n = blockIdx.z;
  int i0 = blockIdx.x * 128, j0 = blockIdx.y * 128;
  __shared__ __align__(16) unsigned short sm[32768];
  f32x4 acc[4][2];
  final_core(Athi + (size_t)n * CC, Atlo + (size_t)n * CC, X + (size_t)n * CD * HW, i0,
             j0, sm, acc);
  epi_store(acc, (float*)sm, out + (size_t)n * CD * HW + (size_t)i0 * HW + j0, HW,
            cv + n * CD + i0);
}

extern "C" void kernel_launch(void* const* d_in, const int* in_sizes, int n_in,
                              void* d_out, int out_size, void* d_ws, size_t ws_size,
                              hipStream_t stream) {
  const float* X = (const float*)d_in[0];
  const float* w0 = (const float*)d_in[1];
  const float* b0 = (const float*)d_in[2];
  const float* w1 = (const float*)d_in[3];
  const float* b1 = (const float*)d_in[4];
  const float* w2 = (const float*)d_in[5];
  const float* b2 = (const float*)d_in[6];
  const float* w3 = (const float*)d_in[7];
  const float* b3 = (const float*)d_in[8];
  float* out = (float*)d_out;
  float* ws = (float*)d_ws;

  float* cv    = ws;
  float* alp   = ws + 1024;
  float* gam   = ws + 2048;
  float* dlt   = ws + 3072;
  float* vp    = ws + 4096;
  float* bpv   = ws + 5120;
  float* scal0 = ws + 6144;
  float* scal1 = ws + 6176;
  unsigned int* barctr = (unsigned int*)(ws + 6208);
  float* psum2 = ws + 8192;                    // NB*KSG*256 = 16384
  float* Et    = psum2 + 16384;
  float* Ff    = Et + CC;
  float* G     = Ff + CC;                      // NB*CC
  float* Gp    = G + (size_t)NB * CC;          // KSG*NB*CC
  unsigned short* Eh   = (unsigned short*)(Gp + (size_t)KSG * NB * CC);
  unsigned short* El   = Eh + CC;
  unsigned short* Fth  = El + CC;
  unsigned short* Ftl  = Fth + CC;
  unsigned short* Gh   = Ftl + CC;
  unsigned short* Gl   = Gh + (size_t)NB * CC;
  unsigned short* Rh   = Gl + (size_t)NB * CC;
  unsigned short* Rl   = Rh + (size_t)NB * CC;
  unsigned short* Athi = Rl + (size_t)NB * CC;
  unsigned short* Atlo = Athi + (size_t)NB * CC;

  kB<<<dim3(213), 512, 0, stream>>>(X, Gp, psum2, w0, w1, w2, w3, b0, b1, b2, Eh, El,
                                    Et, Fth, Ftl, Ff, vp, bpv, dlt, scal1, barctr);
  kCD<<<dim3(100), 512, 0, stream>>>(Gp, G, Gh, Gl, psum2, vp, Ff, Et, alp, gam, scal0,
                                     Eh, El, Rh, Rl, dlt, scal1, b3, cv, Fth, Ftl, Athi,
                                     Atlo, bpv, barctr);
  kF<<<dim3(2, 32, NB), 512, 0, stream>>>(Athi, Atlo, X, cv, out);
}

// Round 13
// 75.145 us; speedup vs baseline: 1.1510x; 1.0992x over previous
//
#include <hip/hip_runtime.h>

#define NB 4
#define CD 256
#define HW 4096
#define KSG 16
#define CC (CD * CD)

typedef __attribute__((ext_vector_type(8))) short bf16x8;
typedef __attribute__((ext_vector_type(4))) float f32x4;

__device__ inline unsigned short f2bf(float x) {
  unsigned int u = __float_as_uint(x);
  unsigned int r = (u + 0x7FFFu + ((u >> 16) & 1u)) >> 16;
  return (unsigned short)r;
}
__device__ inline float bfhi(unsigned short h) {
  return __uint_as_float(((unsigned int)h) << 16);
}
__device__ __forceinline__ void gload16(const unsigned short* g, unsigned short* l) {
  __builtin_amdgcn_global_load_lds((const __attribute__((address_space(1))) void*)g,
                                   (__attribute__((address_space(3))) void*)l, 16, 0, 0);
}

// ---------- MFMA body: A at sm[0]/sm[8192], B at sm[BOFF]/sm[BOFF+8192] ----------
template <int BOFF>
__device__ __forceinline__ void mfma_body(const unsigned short* sm, f32x4 acc[4][2]) {
  int t = threadIdx.x, lane = t & 63, wid = t >> 6;
  int wr = wid >> 2, wc = wid & 3;
  int lrow = lane & 15, lkb = lane >> 4;
#pragma unroll
  for (int ks2 = 0; ks2 < 2; ++ks2) {
    bf16x8 ah[4], al[4], bh[2], bl[2];
#pragma unroll
    for (int m = 0; m < 4; ++m) {
      int r = wr * 64 + m * 16 + lrow;
      int sw = ((ks2 * 4 + lkb) ^ (r & 7)) * 8;
      ah[m] = *(const bf16x8*)(sm + r * 64 + sw);
      al[m] = *(const bf16x8*)(sm + 8192 + r * 64 + sw);
    }
#pragma unroll
    for (int q = 0; q < 2; ++q) {
      int r = wc * 32 + q * 16 + lrow;
      int sw = ((ks2 * 4 + lkb) ^ (r & 7)) * 8;
      bh[q] = *(const bf16x8*)(sm + BOFF + r * 64 + sw);
      bl[q] = *(const bf16x8*)(sm + BOFF + 8192 + r * 64 + sw);
    }
#pragma unroll
    for (int m = 0; m < 4; ++m)
#pragma unroll
      for (int q = 0; q < 2; ++q) {
        acc[m][q] = __builtin_amdgcn_mfma_f32_16x16x32_bf16(ah[m], bh[q], acc[m][q], 0, 0, 0);
        acc[m][q] = __builtin_amdgcn_mfma_f32_16x16x32_bf16(ah[m], bl[q], acc[m][q], 0, 0, 0);
        acc[m][q] = __builtin_amdgcn_mfma_f32_16x16x32_bf16(al[m], bh[q], acc[m][q], 0, 0, 0);
      }
  }
}

// ---------- bf16-operand NT core (gload16 staging) ----------
__device__ __forceinline__ void mfma_nt_core(
    const unsigned short* __restrict__ pH, const unsigned short* __restrict__ pL,
    const unsigned short* __restrict__ qH, const unsigned short* __restrict__ qL,
    int i0, int j0, unsigned short* sm, f32x4 acc[4][2]) {
  int t = threadIdx.x;
  int lane = t & 63, wid = t >> 6;
  int tsel = wid >> 1;
  int gbase = (wid & 1) * 8;
  const unsigned short* bp2 = (tsel == 0) ? pH : (tsel == 1) ? pL : (tsel == 2) ? qH : qL;
  int tb = (tsel < 2) ? i0 : j0;
  int rsub = lane >> 3;
  int gc = (lane & 7) ^ rsub;
  unsigned short* ldsT = sm + tsel * 8192;
#pragma unroll
  for (int m = 0; m < 4; ++m)
#pragma unroll
    for (int q = 0; q < 2; ++q) acc[m][q] = (f32x4){0.f, 0.f, 0.f, 0.f};
  for (int k0 = 0; k0 < 256; k0 += 64) {
#pragma unroll
    for (int s = 0; s < 8; ++s) {
      int g = gbase + s;
      gload16(bp2 + (size_t)(tb + g * 8 + rsub) * CD + k0 + gc * 8, ldsT + g * 512);
    }
    __syncthreads();
    mfma_body<16384>(sm, acc);
    __syncthreads();
  }
}

// ---------- gram core: operands from X fp32, reg-prefetch; DIAG stages A only ----------
template <bool DIAG, int NSTEP>
__device__ __forceinline__ void gram_core(const float* __restrict__ Xn, int i0, int j0,
                                          int kBegin, unsigned short* sm,
                                          f32x4 acc[4][2], float* __restrict__ psumRow) {
  int t = threadIdx.x;
  int r16 = t >> 4, k4 = (t & 15) * 4;
  int kg = k4 >> 3, kr = k4 & 7;
#pragma unroll
  for (int m = 0; m < 4; ++m)
#pragma unroll
    for (int q = 0; q < 2; ++q) acc[m][q] = (f32x4){0.f, 0.f, 0.f, 0.f};
  float ps[4] = {0.f, 0.f, 0.f, 0.f};
  float4 av[4], bv[4];
#pragma unroll
  for (int j = 0; j < 4; ++j) {
    av[j] = *(const float4*)(Xn + (size_t)(i0 + j * 32 + r16) * HW + kBegin + k4);
    if (!DIAG)
      bv[j] = *(const float4*)(Xn + (size_t)(j0 + j * 32 + r16) * HW + kBegin + k4);
  }
#pragma unroll
  for (int s = 0; s < NSTEP; ++s) {
    float4 av2[4], bv2[4];
    if (s < NSTEP - 1) {
#pragma unroll
      for (int j = 0; j < 4; ++j) {
        av2[j] = *(const float4*)(Xn + (size_t)(i0 + j * 32 + r16) * HW + kBegin +
                                  (s + 1) * 64 + k4);
        if (!DIAG)
          bv2[j] = *(const float4*)(Xn + (size_t)(j0 + j * 32 + r16) * HW + kBegin +
                                    (s + 1) * 64 + k4);
      }
    }
#pragma unroll
    for (int j = 0; j < 4; ++j) {
      int r = j * 32 + r16;
      int off = r * 64 + ((kg ^ (r & 7)) << 3) + kr;
      ushort4 h, l;
      h.x = f2bf(av[j].x); l.x = f2bf(av[j].x - bfhi(h.x));
      h.y = f2bf(av[j].y); l.y = f2bf(av[j].y - bfhi(h.y));
      h.z = f2bf(av[j].z); l.z = f2bf(av[j].z - bfhi(h.z));
      h.w = f2bf(av[j].w); l.w = f2bf(av[j].w - bfhi(h.w));
      *(ushort4*)(sm + off) = h;
      *(ushort4*)(sm + 8192 + off) = l;
      ps[j] += av[j].x + av[j].y + av[j].z + av[j].w;
      if (!DIAG) {
        h.x = f2bf(bv[j].x); l.x = f2bf(bv[j].x - bfhi(h.x));
        h.y = f2bf(bv[j].y); l.y = f2bf(bv[j].y - bfhi(h.y));
        h.z = f2bf(bv[j].z); l.z = f2bf(bv[j].z - bfhi(h.z));
        h.w = f2bf(bv[j].w); l.w = f2bf(bv[j].w - bfhi(h.w));
        *(ushort4*)(sm + 16384 + off) = h;
        *(ushort4*)(sm + 24576 + off) = l;
      }
    }
    __syncthreads();
    mfma_body<DIAG ? 0 : 16384>(sm, acc);
    __syncthreads();
    if (s < NSTEP - 1) {
#pragma unroll
      for (int j = 0; j < 4; ++j) {
        av[j] = av2[j];
        if (!DIAG) bv[j] = bv2[j];
      }
    }
  }
  if (psumRow) {
#pragma unroll
    for (int j = 0; j < 4; ++j) {
      float v = ps[j];
      v += __shfl_xor(v, 1); v += __shfl_xor(v, 2);
      v += __shfl_xor(v, 4); v += __shfl_xor(v, 8);
      if ((t & 15) == 0) psumRow[j * 32 + r16] = v;
    }
  }
}

// ---------- ROW-stage: LDS[r][k] = W[r0+r][k0+k] (hi/lo) ----------
__device__ __forceinline__ void stage_rowA(const float* __restrict__ W, int ld, int r0,
                                           int k0, unsigned short* dst) {
  int t = threadIdx.x;
  int r16 = t >> 4, k4 = (t & 15) * 4;
  int kg = k4 >> 3, kr = k4 & 7;
#pragma unroll
  for (int j = 0; j < 4; ++j) {
    int r = j * 32 + r16;
    float4 v = *(const float4*)(W + (size_t)(r0 + r) * ld + k0 + k4);
    int off = r * 64 + ((kg ^ (r & 7)) << 3) + kr;
    ushort4 h, l;
    h.x = f2bf(v.x); l.x = f2bf(v.x - bfhi(h.x));
    h.y = f2bf(v.y); l.y = f2bf(v.y - bfhi(h.y));
    h.z = f2bf(v.z); l.z = f2bf(v.z - bfhi(h.z));
    h.w = f2bf(v.w); l.w = f2bf(v.w - bfhi(h.w));
    *(ushort4*)(dst + off) = h;
    *(ushort4*)(dst + 8192 + off) = l;
  }
}

// ---------- COL-stage (transpose): LDS[c][k] = W[k0+k][c0+c] (hi/lo), 128 cols ----------
__device__ __forceinline__ void stage_colT(const float* __restrict__ W, int ld, int c0,
                                           int k0, unsigned short* dst) {
  int t = threadIdx.x;
#pragma unroll
  for (int ee = 0; ee < 8; ++ee) {
    int flat = ee * 512 + t;
    int c2 = flat >> 7, p = flat & 127;
    const float* src = W + (size_t)(k0 + 2 * c2) * ld + c0 + p;
    float xa = src[0], xb = src[ld];
    int c = 2 * c2;
    int off = p * 64 + ((((c >> 3)) ^ (p & 7)) << 3) + (c & 7);
    unsigned short ha = f2bf(xa), hb = f2bf(xb);
    ushort2 hv; hv.x = ha; hv.y = hb;
    ushort2 lv; lv.x = f2bf(xa - bfhi(ha)); lv.y = f2bf(xb - bfhi(hb));
    *(ushort2*)(dst + off) = hv;
    *(ushort2*)(dst + 8192 + off) = lv;
  }
}

// ---------- final core: A = At bf16 via gload16; B = X fp32 transpose-staged w/ prefetch ----------
__device__ __forceinline__ void final_core(const unsigned short* __restrict__ aH,
                                           const unsigned short* __restrict__ aL,
                                           const float* __restrict__ Xn, int i0, int j0,
                                           unsigned short* sm, f32x4 acc[4][2]) {
  int t = threadIdx.x, lane = t & 63, wid = t >> 6;
  const unsigned short* ap = (wid & 4) ? aL : aH;
  unsigned short* ldsA = sm + ((wid & 4) ? 8192 : 0);
  int rsub = lane >> 3;
  int gc = (lane & 7) ^ rsub;
  int gq = wid & 3;
#pragma unroll
  for (int m = 0; m < 4; ++m)
#pragma unroll
    for (int q = 0; q < 2; ++q) acc[m][q] = (f32x4){0.f, 0.f, 0.f, 0.f};
  float xa[8], xb[8];
#pragma unroll
  for (int s2 = 0; s2 < 4; ++s2) {
    int g = gq * 4 + s2;
    gload16(ap + (size_t)(i0 + g * 8 + rsub) * CD + gc * 8, ldsA + g * 512);
  }
#pragma unroll
  for (int ee = 0; ee < 8; ++ee) {
    int flat = ee * 512 + t;
    int c2 = flat >> 7, p = flat & 127;
    const float* src = Xn + (size_t)(2 * c2) * HW + j0 + p;
    xa[ee] = src[0];
    xb[ee] = src[HW];
  }
#pragma unroll
  for (int s = 0; s < 4; ++s) {
#pragma unroll
    for (int ee = 0; ee < 8; ++ee) {
      int flat = ee * 512 + t;
      int c2 = flat >> 7, p = flat & 127;
      int c = 2 * c2;
      int off = p * 64 + ((((c >> 3)) ^ (p & 7)) << 3) + (c & 7);
      unsigned short ha = f2bf(xa[ee]), hb = f2bf(xb[ee]);
      ushort2 hv; hv.x = ha; hv.y = hb;
      ushort2 lv; lv.x = f2bf(xa[ee] - bfhi(ha)); lv.y = f2bf(xb[ee] - bfhi(hb));
      *(ushort2*)(sm + 16384 + off) = hv;
      *(ushort2*)(sm + 24576 + off) = lv;
    }
    float xa2[8], xb2[8];
    if (s < 3) {
#pragma unroll
      for (int ee = 0; ee < 8; ++ee) {
        int flat = ee * 512 + t;
        int c2 = flat >> 7, p = flat & 127;
        const float* src = Xn + (size_t)((s + 1) * 64 + 2 * c2) * HW + j0 + p;
        xa2[ee] = src[0];
        xb2[ee] = src[HW];
      }
    }
    __syncthreads();
    mfma_body<16384>(sm, acc);
    __syncthreads();
    if (s < 3) {
#pragma unroll
      for (int s2 = 0; s2 < 4; ++s2) {
        int g = gq * 4 + s2;
        gload16(ap + (size_t)(i0 + g * 8 + rsub) * CD + (s + 1) * 64 + gc * 8,
                ldsA + g * 512);
      }
#pragma unroll
      for (int ee = 0; ee < 8; ++ee) { xa[ee] = xa2[ee]; xb[ee] = xb2[ee]; }
    }
  }
}

// ---------- coalesced fp32 epilogue ----------
__device__ __forceinline__ void epi_store(f32x4 acc[4][2], float* smf, float* dst,
                                          int ld, const float* cvrow) {
  int t = threadIdx.x, lane = t & 63, wid = t >> 6;
  int wr = wid >> 2, wc = wid & 3;
#pragma unroll
  for (int m = 0; m < 4; ++m) {
    int rbase = wr * 64 + m * 16 + ((lane >> 4) << 2);
#pragma unroll
    for (int q = 0; q < 2; ++q) {
      int col = wc * 32 + q * 16 + (lane & 15);
#pragma unroll
      for (int e = 0; e < 4; ++e) {
        int row = rbase + e;
        smf[row * 128 + (col ^ ((row & 4) << 2))] = acc[m][q][e];
      }
    }
  }
  __syncthreads();
#pragma unroll
  for (int it = 0; it < 8; ++it) {
    int row = it * 16 + wid * 2 + (lane >> 5);
    int col = (lane & 31) * 4;
    float4 v = *(const float4*)&smf[row * 128 + (col ^ ((row & 4) << 2))];
    if (cvrow) {
      float cb = cvrow[row];
      v.x += cb; v.y += cb; v.z += cb; v.w += cb;
    }
    *(float4*)(dst + (size_t)row * ld + col) = v;
  }
}

// ---------- kB: gram (192) + EF on-the-fly (8) + small vectors (13) ----------
__global__ __launch_bounds__(512) void kB(
    const float* __restrict__ X, float* __restrict__ Gp, float* __restrict__ psum2,
    const float* __restrict__ w0, const float* __restrict__ w1,
    const float* __restrict__ w2, const float* __restrict__ w3,
    const float* __restrict__ b0, const float* __restrict__ b1,
    const float* __restrict__ b2, unsigned short* __restrict__ Eh,
    unsigned short* __restrict__ El, float* __restrict__ Et,
    unsigned short* __restrict__ Fth, unsigned short* __restrict__ Ftl,
    float* __restrict__ Ff, float* __restrict__ vp, float* __restrict__ bpv,
    float* __restrict__ dlt, float* __restrict__ scal1) {
  __shared__ __align__(16) unsigned short sm[32768];
  int x = blockIdx.x, t = threadIdx.x;
  if (x < 192) {
    int tile = x % 3;  // 0: (0,0) diag, 1: (0,128), 2: (128,128) diag
    int z = x / 3;
    int n = z >> 4, ks = z & 15;
    const float* Xn = X + (size_t)n * CD * HW;
    f32x4 acc[4][2];
    if (tile == 1) {
      gram_core<false, 4>(Xn, 0, 128, ks * 256, sm, acc, nullptr);
      epi_store(acc, (float*)sm, Gp + ((size_t)ks * NB + n) * CC + 128, CD, nullptr);
    } else {
      int i0 = (tile == 2) ? 128 : 0;
      float* psRow = psum2 + ((size_t)n * KSG + ks) * 256 + i0;
      gram_core<true, 4>(Xn, i0, i0, ks * 256, sm, acc, psRow);
      epi_store(acc, (float*)sm,
                Gp + ((size_t)ks * NB + n) * CC + (size_t)i0 * CD + i0, CD, nullptr);
    }
  } else if (x < 200) {
    int e = x - 192;
    int zc = e >> 2, q = e & 3;
    int i0 = (q >> 1) * 128, j0 = (q & 1) * 128;
    f32x4 acc[4][2];
#pragma unroll
    for (int m = 0; m < 4; ++m)
#pragma unroll
      for (int qq = 0; qq < 2; ++qq) acc[m][qq] = (f32x4){0.f, 0.f, 0.f, 0.f};
    for (int s = 0; s < 4; ++s) {
      int k0 = s * 64;
      if (zc == 0) stage_rowA(w3, CD, i0, k0, sm);
      else stage_colT(w2, CD, i0, k0, sm);
      stage_colT(zc ? w1 : w0, CD, j0, k0, sm + 16384);
      __syncthreads();
      mfma_body<16384>(sm, acc);
      __syncthreads();
    }
    unsigned short* oh = zc ? Fth : Eh;
    unsigned short* ol = zc ? Ftl : El;
    float* tf = zc ? Ff : Et;
    int lane = t & 63, wid = t >> 6, wr = wid >> 2, wc = wid & 3;
#pragma unroll
    for (int m = 0; m < 4; ++m) {
      int row = i0 + wr * 64 + m * 16 + ((lane >> 4) << 2);
#pragma unroll
      for (int q2 = 0; q2 < 2; ++q2) {
        int col = j0 + wc * 32 + q2 * 16 + (lane & 15);
#pragma unroll
        for (int e2 = 0; e2 < 4; ++e2) {
          float v = acc[m][q2][e2];
          unsigned short hh = f2bf(v), ll = f2bf(v - bfhi(hh));
          oh[(size_t)(row + e2) * CD + col] = hh;
          ol[(size_t)(row + e2) * CD + col] = ll;
          tf[(size_t)col * CD + row + e2] = v;
        }
      }
    }
  } else {
    int task = x - 200;
    if (task < 8) {
      float* vin = (float*)sm;
      int seg = task & 3;
      const float* Wm = (task < 4) ? w1 : w2;
      const float* v = (task < 4) ? b2 : b1;
      float* dst = (task < 4) ? (vp + seg * CD) : (bpv + seg * CD);
      if (t < 64) vin[t] = v[seg * 64 + t];
      __syncthreads();
      if (t < 256) {
        float a = 0.f;
#pragma unroll 16
        for (int kk = 0; kk < 64; ++kk)
          a += Wm[(size_t)(seg * 64 + kk) * CD + t] * vin[kk];
        dst[t] = a;
      }
    } else if (task < 12) {
      int lane = t & 63, wv = t >> 6;
      float4 bvv = *(const float4*)(b0 + lane * 4);
#pragma unroll
      for (int i = 0; i < 8; ++i) {
        int o = (task - 8) * 64 + wv * 8 + i;
        float4 v = *(const float4*)(w3 + (size_t)o * CD + lane * 4);
        float a = v.x * bvv.x + v.y * bvv.y + v.z * bvv.z + v.w * bvv.w;
        a += __shfl_xor(a, 1);  a += __shfl_xor(a, 2);  a += __shfl_xor(a, 4);
        a += __shfl_xor(a, 8);  a += __shfl_xor(a, 16); a += __shfl_xor(a, 32);
        if (lane == 0) dlt[o] = a;
      }
    } else if (task == 12) {
      float* red = (float*)sm;
      if (t < 256) red[t] = b1[t] * b2[t];
      __syncthreads();
      for (int off = 128; off > 0; off >>= 1) {
        if (t < off) red[t] += red[t + off];
        __syncthreads();
      }
      if (t == 0) scal1[0] = red[0];
    }
  }
}

// ---------- kC: gram reduce (+mirror) -> bf16 hi/lo only + sag (100 blocks) ----------
__global__ __launch_bounds__(512) void kC(
    const float* __restrict__ Gp, unsigned short* __restrict__ Gh,
    unsigned short* __restrict__ Gl, const float* __restrict__ psum2,
    const float* __restrict__ vp, const float* __restrict__ Ff,
    const float* __restrict__ Et, float* __restrict__ alp, float* __restrict__ gam,
    float* __restrict__ scal0) {
  __shared__ float smf[512];
  int b = blockIdx.x, t = threadIdx.x;
  if (b < 96) {
#pragma unroll
    for (int s = 0; s < 4; ++s) {
      int f = b * 2048 + s * 512 + t;
      int b2 = f >> 8, tt = f & 255;
      int quad = b2 >> 8, r = b2 & 255, n = r >> 6;
      int idx = (r & 63) * 256 + tt;
      int i = (idx >> 7) + ((quad == 2) ? 128 : 0);
      int j = (idx & 127) + ((quad >= 1) ? 128 : 0);
      float a = 0.f;
#pragma unroll
      for (int ks = 0; ks < KSG; ++ks)
        a += Gp[((size_t)ks * NB + n) * CC + (size_t)i * CD + j];
      size_t o = (size_t)n * CC + (size_t)i * CD + j;
      unsigned short hh = f2bf(a), ll = f2bf(a - bfhi(hh));
      Gh[o] = hh; Gl[o] = ll;
      if (quad == 1) {
        size_t o2 = (size_t)n * CC + (size_t)j * CD + i;
        Gh[o2] = hh; Gl[o2] = ll;
      }
    }
  } else {
    int n = b - 96;
    float* ss = smf;
    float* red = ss + 256;
    float a = 0.f;
    if (t < 256) {
#pragma unroll
      for (int ks = 0; ks < KSG; ++ks) a += psum2[((size_t)n * KSG + ks) * 256 + t];
      ss[t] = a;
      red[t] = a * (vp[t] + vp[CD + t] + vp[2 * CD + t] + vp[3 * CD + t]);
    }
    __syncthreads();
    for (int off = 128; off > 0; off >>= 1) {
      if (t < off) red[t] += red[t + off];
      __syncthreads();
    }
    if (t == 0) scal0[n] = red[0];
    if (t < 256) {
      float al = 0.f, ga = 0.f;
#pragma unroll 16
      for (int k = 0; k < CD; ++k) {
        float sk = ss[k];
        al += Ff[(size_t)k * CD + t] * sk;
        ga += Et[(size_t)k * CD + t] * sk;
      }
      alp[n * CD + t] = al;
      gam[n * CD + t] = ga;
    }
  }
}

// ---------- kD1: Rm (16 blocks) + cv (4 blocks, G reconstructed from Gh/Gl) ----------
__global__ __launch_bounds__(512) void kD1(
    const unsigned short* __restrict__ Eh, const unsigned short* __restrict__ El,
    const unsigned short* __restrict__ Gh, const unsigned short* __restrict__ Gl,
    unsigned short* __restrict__ Rh, unsigned short* __restrict__ Rl,
    const float* __restrict__ Et, const float* __restrict__ vp,
    const float* __restrict__ dlt, const float* __restrict__ gam,
    const float* __restrict__ scal0, const float* __restrict__ scal1,
    const float* __restrict__ b3, float* __restrict__ cv) {
  __shared__ __align__(16) unsigned short sm[32768];
  int b = blockIdx.x, t = threadIdx.x;
  if (b < 16) {
    int n = b >> 2, i0 = ((b >> 1) & 1) * 128, j0 = (b & 1) * 128;
    f32x4 acc[4][2];
    mfma_nt_core(Eh, El, Gh + (size_t)n * CC, Gl + (size_t)n * CC, i0, j0, sm, acc);
    int lane = t & 63, wid = t >> 6, wr = wid >> 2, wc = wid & 3;
#pragma unroll
    for (int m = 0; m < 4; ++m) {
      int row = i0 + wr * 64 + m * 16 + ((lane >> 4) << 2);
#pragma unroll
      for (int q = 0; q < 2; ++q) {
        int col = j0 + wc * 32 + q * 16 + (lane & 15);
#pragma unroll
        for (int e = 0; e < 4; ++e) {
          float v = acc[m][q][e];
          unsigned short hh = f2bf(v), ll = f2bf(v - bfhi(hh));
          Rh[(size_t)n * CC + (size_t)(row + e) * CD + col] = hh;
          Rl[(size_t)n * CC + (size_t)(row + e) * CD + col] = ll;
        }
      }
    }
  } else {
    int n = b - 16;
    float* vsh = (float*)sm;
    float* g1 = vsh + CD;
    if (t < CD) vsh[t] = vp[t] + vp[CD + t] + vp[2 * CD + t] + vp[3 * CD + t];
    __syncthreads();
    if (t < CD) {
      const unsigned short* GhN = Gh + (size_t)n * CC;
      const unsigned short* GlN = Gl + (size_t)n * CC;
      float a = 0.f;
#pragma unroll 8
      for (int k = 0; k < CD; ++k) {
        float g = bfhi(GhN[(size_t)k * CD + t]) + bfhi(GlN[(size_t)k * CD + t]);
        a += g * vsh[k];
      }
      g1[t] = a;
    }
    __syncthreads();
    if (t < CD) {
      float c2 = 0.f;
#pragma unroll 8
      for (int k = 0; k < CD; ++k) c2 += Et[(size_t)k * CD + t] * g1[k];
      cv[n * CD + t] = (c2 + scal0[n] * dlt[t] +
                        scal1[0] * (gam[n * CD + t] + (float)HW * dlt[t])) *
                           (1.0f / HW) +
                       b3[t];
    }
  }
}

// ---------- kD2: Atm (16 blocks) ----------
__global__ __launch_bounds__(512) void kD2(
    const unsigned short* __restrict__ Rh, const unsigned short* __restrict__ Rl,
    const unsigned short* __restrict__ Fth, const unsigned short* __restrict__ Ftl,
    unsigned short* __restrict__ Athi, unsigned short* __restrict__ Atlo,
    const float* __restrict__ dlt, const float* __restrict__ alp,
    const float* __restrict__ gam, const float* __restrict__ bpv) {
  __shared__ __align__(16) unsigned short sm[32768];
  int b = blockIdx.x, t = threadIdx.x;
  int n = b >> 2, i0 = ((b >> 1) & 1) * 128, j0 = (b & 1) * 128;
  f32x4 acc[4][2];
  mfma_nt_core(Rh + (size_t)n * CC, Rl + (size_t)n * CC, Fth, Ftl, i0, j0, sm, acc);
  int lane = t & 63, wid = t >> 6, wr = wid >> 2, wc = wid & 3;
#pragma unroll
  for (int m = 0; m < 4; ++m) {
    int row = i0 + wr * 64 + m * 16 + ((lane >> 4) << 2);
#pragma unroll
    for (int q = 0; q < 2; ++q) {
      int col = j0 + wc * 32 + q * 16 + (lane & 15);
      float bj = bpv[col] + bpv[CD + col] + bpv[2 * CD + col] + bpv[3 * CD + col];
      float aj = alp[n * CD + col];
#pragma unroll
      for (int e = 0; e < 4; ++e) {
        float di = dlt[row + e], gi = gam[n * CD + row + e];
        float v = (acc[m][q][e] + di * aj + gi * bj) * (1.0f / HW) + di * bj;
        unsigned short hh = f2bf(v), ll = f2bf(v - bfhi(hh));
        Athi[(size_t)n * CC + (size_t)(row + e) * CD + col] = hh;
        Atlo[(size_t)n * CC + (size_t)(row + e) * CD + col] = ll;
      }
    }
  }
}

// ---------- kF: out = At x X (B transposed+split on the fly, prefetched) + cv ----------
__global__ __launch_bounds__(512) void kF(const unsigned short* __restrict__ Athi,
                                          const unsigned short* __restrict__ Atlo,
                                          const float* __restrict__ X,
                                          const float* __restrict__ cv,
                                          float* __restrict__ out) {
  int n = blockIdx.z;
  int i0 = blockIdx.x * 128, j0 = blockIdx.y * 128;
  __shared__ __align__(16) unsigned short sm[32768];
  f32x4 acc[4][2];
  final_core(Athi + (size_t)n * CC, Atlo + (size_t)n * CC, X + (size_t)n * CD * HW, i0,
             j0, sm, acc);
  epi_store(acc, (float*)sm, out + (size_t)n * CD * HW + (size_t)i0 * HW + j0, HW,
            cv + n * CD + i0);
}

extern "C" void kernel_launch(void* const* d_in, const int* in_sizes, int n_in,
                              void* d_out, int out_size, void* d_ws, size_t ws_size,
                              hipStream_t stream) {
  const float* X = (const float*)d_in[0];
  const float* w0 = (const float*)d_in[1];
  const float* b0 = (const float*)d_in[2];
  const float* w1 = (const float*)d_in[3];
  const float* b1 = (const float*)d_in[4];
  const float* w2 = (const float*)d_in[5];
  const float* b2 = (const float*)d_in[6];
  const float* w3 = (const float*)d_in[7];
  const float* b3 = (const float*)d_in[8];
  float* out = (float*)d_out;
  float* ws = (float*)d_ws;

  float* cv    = ws;
  float* alp   = ws + 1024;
  float* gam   = ws + 2048;
  float* dlt   = ws + 3072;
  float* vp    = ws + 4096;
  float* bpv   = ws + 5120;
  float* scal0 = ws + 6144;
  float* scal1 = ws + 6176;
  float* psum2 = ws + 8192;                    // NB*KSG*256 = 16384
  float* Et    = psum2 + 16384;
  float* Ff    = Et + CC;
  float* Gp    = Ff + CC;                      // KSG*NB*CC
  unsigned short* Eh   = (unsigned short*)(Gp + (size_t)KSG * NB * CC);
  unsigned short* El   = Eh + CC;
  unsigned short* Fth  = El + CC;
  unsigned short* Ftl  = Fth + CC;
  unsigned short* Gh   = Ftl + CC;
  unsigned short* Gl   = Gh + (size_t)NB * CC;
  unsigned short* Rh   = Gl + (size_t)NB * CC;
  unsigned short* Rl   = Rh + (size_t)NB * CC;
  unsigned short* Athi = Rl + (size_t)NB * CC;
  unsigned short* Atlo = Athi + (size_t)NB * CC;

  kB<<<dim3(213), 512, 0, stream>>>(X, Gp, psum2, w0, w1, w2, w3, b0, b1, b2, Eh, El,
                                    Et, Fth, Ftl, Ff, vp, bpv, dlt, scal1);
  kC<<<dim3(100), 512, 0, stream>>>(Gp, Gh, Gl, psum2, vp, Ff, Et, alp, gam, scal0);
  kD1<<<dim3(20), 512, 0, stream>>>(Eh, El, Gh, Gl, Rh, Rl, Et, vp, dlt, gam, scal0,
                                    scal1, b3, cv);
  kD2<<<dim3(16), 512, 0, stream>>>(Rh, Rl, Fth, Ftl, Athi, Atlo, dlt, alp, gam, bpv);
  kF<<<dim3(2, 32, NB), 512, 0, stream>>>(Athi, Atlo, X, cv, out);
}

// Round 14
// 74.870 us; speedup vs baseline: 1.1553x; 1.0037x over previous
//
#include <hip/hip_runtime.h>

#define NB 4
#define CD 256
#define HW 4096
#define KSG 16
#define CC (CD * CD)

typedef __attribute__((ext_vector_type(8))) short bf16x8;
typedef __attribute__((ext_vector_type(4))) float f32x4;

__device__ inline unsigned short f2bf(float x) {
  unsigned int u = __float_as_uint(x);
  unsigned int r = (u + 0x7FFFu + ((u >> 16) & 1u)) >> 16;
  return (unsigned short)r;
}
__device__ inline float bfhi(unsigned short h) {
  return __uint_as_float(((unsigned int)h) << 16);
}
__device__ __forceinline__ void gload16(const unsigned short* g, unsigned short* l) {
  __builtin_amdgcn_global_load_lds((const __attribute__((address_space(1))) void*)g,
                                   (__attribute__((address_space(3))) void*)l, 16, 0, 0);
}

// ---------- MFMA body: A at sm[0]/sm[8192], B at sm[BOFF]/sm[BOFF+8192] ----------
template <int BOFF>
__device__ __forceinline__ void mfma_body(const unsigned short* sm, f32x4 acc[4][2]) {
  int t = threadIdx.x, lane = t & 63, wid = t >> 6;
  int wr = wid >> 2, wc = wid & 3;
  int lrow = lane & 15, lkb = lane >> 4;
#pragma unroll
  for (int ks2 = 0; ks2 < 2; ++ks2) {
    bf16x8 ah[4], al[4], bh[2], bl[2];
#pragma unroll
    for (int m = 0; m < 4; ++m) {
      int r = wr * 64 + m * 16 + lrow;
      int sw = ((ks2 * 4 + lkb) ^ (r & 7)) * 8;
      ah[m] = *(const bf16x8*)(sm + r * 64 + sw);
      al[m] = *(const bf16x8*)(sm + 8192 + r * 64 + sw);
    }
#pragma unroll
    for (int q = 0; q < 2; ++q) {
      int r = wc * 32 + q * 16 + lrow;
      int sw = ((ks2 * 4 + lkb) ^ (r & 7)) * 8;
      bh[q] = *(const bf16x8*)(sm + BOFF + r * 64 + sw);
      bl[q] = *(const bf16x8*)(sm + BOFF + 8192 + r * 64 + sw);
    }
#pragma unroll
    for (int m = 0; m < 4; ++m)
#pragma unroll
      for (int q = 0; q < 2; ++q) {
        acc[m][q] = __builtin_amdgcn_mfma_f32_16x16x32_bf16(ah[m], bh[q], acc[m][q], 0, 0, 0);
        acc[m][q] = __builtin_amdgcn_mfma_f32_16x16x32_bf16(ah[m], bl[q], acc[m][q], 0, 0, 0);
        acc[m][q] = __builtin_amdgcn_mfma_f32_16x16x32_bf16(al[m], bh[q], acc[m][q], 0, 0, 0);
      }
  }
}

// ---------- bf16-operand NT core (gload16 staging) ----------
__device__ __forceinline__ void mfma_nt_core(
    const unsigned short* __restrict__ pH, const unsigned short* __restrict__ pL,
    const unsigned short* __restrict__ qH, const unsigned short* __restrict__ qL,
    int i0, int j0, unsigned short* sm, f32x4 acc[4][2]) {
  int t = threadIdx.x;
  int lane = t & 63, wid = t >> 6;
  int tsel = wid >> 1;
  int gbase = (wid & 1) * 8;
  const unsigned short* bp2 = (tsel == 0) ? pH : (tsel == 1) ? pL : (tsel == 2) ? qH : qL;
  int tb = (tsel < 2) ? i0 : j0;
  int rsub = lane >> 3;
  int gc = (lane & 7) ^ rsub;
  unsigned short* ldsT = sm + tsel * 8192;
#pragma unroll
  for (int m = 0; m < 4; ++m)
#pragma unroll
    for (int q = 0; q < 2; ++q) acc[m][q] = (f32x4){0.f, 0.f, 0.f, 0.f};
  for (int k0 = 0; k0 < 256; k0 += 64) {
#pragma unroll
    for (int s = 0; s < 8; ++s) {
      int g = gbase + s;
      gload16(bp2 + (size_t)(tb + g * 8 + rsub) * CD + k0 + gc * 8, ldsT + g * 512);
    }
    __syncthreads();
    mfma_body<16384>(sm, acc);
    __syncthreads();
  }
}

// ---------- gram core: operands from X fp32, reg-prefetch; DIAG stages A only ----------
template <bool DIAG, int NSTEP>
__device__ __forceinline__ void gram_core(const float* __restrict__ Xn, int i0, int j0,
                                          int kBegin, unsigned short* sm,
                                          f32x4 acc[4][2], float* __restrict__ psumRow) {
  int t = threadIdx.x;
  int r16 = t >> 4, k4 = (t & 15) * 4;
  int kg = k4 >> 3, kr = k4 & 7;
#pragma unroll
  for (int m = 0; m < 4; ++m)
#pragma unroll
    for (int q = 0; q < 2; ++q) acc[m][q] = (f32x4){0.f, 0.f, 0.f, 0.f};
  float ps[4] = {0.f, 0.f, 0.f, 0.f};
  float4 av[4], bv[4];
#pragma unroll
  for (int j = 0; j < 4; ++j) {
    av[j] = *(const float4*)(Xn + (size_t)(i0 + j * 32 + r16) * HW + kBegin + k4);
    if (!DIAG)
      bv[j] = *(const float4*)(Xn + (size_t)(j0 + j * 32 + r16) * HW + kBegin + k4);
  }
#pragma unroll
  for (int s = 0; s < NSTEP; ++s) {
    float4 av2[4], bv2[4];
    if (s < NSTEP - 1) {
#pragma unroll
      for (int j = 0; j < 4; ++j) {
        av2[j] = *(const float4*)(Xn + (size_t)(i0 + j * 32 + r16) * HW + kBegin +
                                  (s + 1) * 64 + k4);
        if (!DIAG)
          bv2[j] = *(const float4*)(Xn + (size_t)(j0 + j * 32 + r16) * HW + kBegin +
                                    (s + 1) * 64 + k4);
      }
    }
#pragma unroll
    for (int j = 0; j < 4; ++j) {
      int r = j * 32 + r16;
      int off = r * 64 + ((kg ^ (r & 7)) << 3) + kr;
      ushort4 h, l;
      h.x = f2bf(av[j].x); l.x = f2bf(av[j].x - bfhi(h.x));
      h.y = f2bf(av[j].y); l.y = f2bf(av[j].y - bfhi(h.y));
      h.z = f2bf(av[j].z); l.z = f2bf(av[j].z - bfhi(h.z));
      h.w = f2bf(av[j].w); l.w = f2bf(av[j].w - bfhi(h.w));
      *(ushort4*)(sm + off) = h;
      *(ushort4*)(sm + 8192 + off) = l;
      ps[j] += av[j].x + av[j].y + av[j].z + av[j].w;
      if (!DIAG) {
        h.x = f2bf(bv[j].x); l.x = f2bf(bv[j].x - bfhi(h.x));
        h.y = f2bf(bv[j].y); l.y = f2bf(bv[j].y - bfhi(h.y));
        h.z = f2bf(bv[j].z); l.z = f2bf(bv[j].z - bfhi(h.z));
        h.w = f2bf(bv[j].w); l.w = f2bf(bv[j].w - bfhi(h.w));
        *(ushort4*)(sm + 16384 + off) = h;
        *(ushort4*)(sm + 24576 + off) = l;
      }
    }
    __syncthreads();
    mfma_body<DIAG ? 0 : 16384>(sm, acc);
    __syncthreads();
    if (s < NSTEP - 1) {
#pragma unroll
      for (int j = 0; j < 4; ++j) {
        av[j] = av2[j];
        if (!DIAG) bv[j] = bv2[j];
      }
    }
  }
  if (psumRow) {
#pragma unroll
    for (int j = 0; j < 4; ++j) {
      float v = ps[j];
      v += __shfl_xor(v, 1); v += __shfl_xor(v, 2);
      v += __shfl_xor(v, 4); v += __shfl_xor(v, 8);
      if ((t & 15) == 0) psumRow[j * 32 + r16] = v;
    }
  }
}

// ---------- ROW-stage: LDS[r][k] = W[r0+r][k0+k] (hi/lo) ----------
__device__ __forceinline__ void stage_rowA(const float* __restrict__ W, int ld, int r0,
                                           int k0, unsigned short* dst) {
  int t = threadIdx.x;
  int r16 = t >> 4, k4 = (t & 15) * 4;
  int kg = k4 >> 3, kr = k4 & 7;
#pragma unroll
  for (int j = 0; j < 4; ++j) {
    int r = j * 32 + r16;
    float4 v = *(const float4*)(W + (size_t)(r0 + r) * ld + k0 + k4);
    int off = r * 64 + ((kg ^ (r & 7)) << 3) + kr;
    ushort4 h, l;
    h.x = f2bf(v.x); l.x = f2bf(v.x - bfhi(h.x));
    h.y = f2bf(v.y); l.y = f2bf(v.y - bfhi(h.y));
    h.z = f2bf(v.z); l.z = f2bf(v.z - bfhi(h.z));
    h.w = f2bf(v.w); l.w = f2bf(v.w - bfhi(h.w));
    *(ushort4*)(dst + off) = h;
    *(ushort4*)(dst + 8192 + off) = l;
  }
}

// ---------- COL-stage (transpose): LDS[c][k] = W[k0+k][c0+c] (hi/lo), 128 cols ----------
__device__ __forceinline__ void stage_colT(const float* __restrict__ W, int ld, int c0,
                                           int k0, unsigned short* dst) {
  int t = threadIdx.x;
#pragma unroll
  for (int ee = 0; ee < 8; ++ee) {
    int flat = ee * 512 + t;
    int c2 = flat >> 7, p = flat & 127;
    const float* src = W + (size_t)(k0 + 2 * c2) * ld + c0 + p;
    float xa = src[0], xb = src[ld];
    int c = 2 * c2;
    int off = p * 64 + ((((c >> 3)) ^ (p & 7)) << 3) + (c & 7);
    unsigned short ha = f2bf(xa), hb = f2bf(xb);
    ushort2 hv; hv.x = ha; hv.y = hb;
    ushort2 lv; lv.x = f2bf(xa - bfhi(ha)); lv.y = f2bf(xb - bfhi(hb));
    *(ushort2*)(dst + off) = hv;
    *(ushort2*)(dst + 8192 + off) = lv;
  }
}

// ---------- kF MFMA body: A 128 rows @0/+8192, B 64 rows @16384/+4096 ----------
__device__ __forceinline__ void mfma_body64(const unsigned short* sm, f32x4 acc[4]) {
  int t = threadIdx.x, lane = t & 63, wid = t >> 6;
  int wr = wid >> 2, wc = wid & 3;
  int lrow = lane & 15, lkb = lane >> 4;
#pragma unroll
  for (int ks2 = 0; ks2 < 2; ++ks2) {
    bf16x8 ah[4], al[4], bh, bl;
#pragma unroll
    for (int m = 0; m < 4; ++m) {
      int r = wr * 64 + m * 16 + lrow;
      int sw = ((ks2 * 4 + lkb) ^ (r & 7)) * 8;
      ah[m] = *(const bf16x8*)(sm + r * 64 + sw);
      al[m] = *(const bf16x8*)(sm + 8192 + r * 64 + sw);
    }
    {
      int r = wc * 16 + lrow;
      int sw = ((ks2 * 4 + lkb) ^ (r & 7)) * 8;
      bh = *(const bf16x8*)(sm + 16384 + r * 64 + sw);
      bl = *(const bf16x8*)(sm + 20480 + r * 64 + sw);
    }
#pragma unroll
    for (int m = 0; m < 4; ++m) {
      acc[m] = __builtin_amdgcn_mfma_f32_16x16x32_bf16(ah[m], bh, acc[m], 0, 0, 0);
      acc[m] = __builtin_amdgcn_mfma_f32_16x16x32_bf16(ah[m], bl, acc[m], 0, 0, 0);
      acc[m] = __builtin_amdgcn_mfma_f32_16x16x32_bf16(al[m], bh, acc[m], 0, 0, 0);
    }
  }
}

// ---------- kF core (64-col B): A = At via gload16; B = X fp32 transpose-staged ----------
__device__ __forceinline__ void final_core64(const unsigned short* __restrict__ aH,
                                             const unsigned short* __restrict__ aL,
                                             const float* __restrict__ Xn, int i0, int j0,
                                             unsigned short* sm, f32x4 acc[4]) {
  int t = threadIdx.x, lane = t & 63, wid = t >> 6;
  const unsigned short* ap = (wid & 4) ? aL : aH;
  unsigned short* ldsA = sm + ((wid & 4) ? 8192 : 0);
  int rsub = lane >> 3;
  int gc = (lane & 7) ^ rsub;
  int gq = wid & 3;
#pragma unroll
  for (int m = 0; m < 4; ++m) acc[m] = (f32x4){0.f, 0.f, 0.f, 0.f};
  float xa[4], xb[4];
#pragma unroll
  for (int s2 = 0; s2 < 4; ++s2) {
    int g = gq * 4 + s2;
    gload16(ap + (size_t)(i0 + g * 8 + rsub) * CD + gc * 8, ldsA + g * 512);
  }
#pragma unroll
  for (int ee = 0; ee < 4; ++ee) {
    int flat = ee * 512 + t;
    int c2 = flat >> 6, p = flat & 63;
    const float* src = Xn + (size_t)(2 * c2) * HW + j0 + p;
    xa[ee] = src[0];
    xb[ee] = src[HW];
  }
#pragma unroll
  for (int s = 0; s < 4; ++s) {
#pragma unroll
    for (int ee = 0; ee < 4; ++ee) {
      int flat = ee * 512 + t;
      int c2 = flat >> 6, p = flat & 63;
      int c = 2 * c2;
      int off = p * 64 + ((((c >> 3)) ^ (p & 7)) << 3) + (c & 7);
      unsigned short ha = f2bf(xa[ee]), hb = f2bf(xb[ee]);
      ushort2 hv; hv.x = ha; hv.y = hb;
      ushort2 lv; lv.x = f2bf(xa[ee] - bfhi(ha)); lv.y = f2bf(xb[ee] - bfhi(hb));
      *(ushort2*)(sm + 16384 + off) = hv;
      *(ushort2*)(sm + 20480 + off) = lv;
    }
    float xa2[4], xb2[4];
    if (s < 3) {
#pragma unroll
      for (int ee = 0; ee < 4; ++ee) {
        int flat = ee * 512 + t;
        int c2 = flat >> 6, p = flat & 63;
        const float* src = Xn + (size_t)((s + 1) * 64 + 2 * c2) * HW + j0 + p;
        xa2[ee] = src[0];
        xb2[ee] = src[HW];
      }
    }
    __syncthreads();
    mfma_body64(sm, acc);
    __syncthreads();
    if (s < 3) {
#pragma unroll
      for (int s2 = 0; s2 < 4; ++s2) {
        int g = gq * 4 + s2;
        gload16(ap + (size_t)(i0 + g * 8 + rsub) * CD + (s + 1) * 64 + gc * 8,
                ldsA + g * 512);
      }
#pragma unroll
      for (int ee = 0; ee < 4; ++ee) { xa[ee] = xa2[ee]; xb[ee] = xb2[ee]; }
    }
  }
}

// ---------- coalesced fp32 epilogue (128x128 tile, kB) ----------
__device__ __forceinline__ void epi_store(f32x4 acc[4][2], float* smf, float* dst,
                                          int ld, const float* cvrow) {
  int t = threadIdx.x, lane = t & 63, wid = t >> 6;
  int wr = wid >> 2, wc = wid & 3;
#pragma unroll
  for (int m = 0; m < 4; ++m) {
    int rbase = wr * 64 + m * 16 + ((lane >> 4) << 2);
#pragma unroll
    for (int q = 0; q < 2; ++q) {
      int col = wc * 32 + q * 16 + (lane & 15);
#pragma unroll
      for (int e = 0; e < 4; ++e) {
        int row = rbase + e;
        smf[row * 128 + (col ^ ((row & 4) << 2))] = acc[m][q][e];
      }
    }
  }
  __syncthreads();
#pragma unroll
  for (int it = 0; it < 8; ++it) {
    int row = it * 16 + wid * 2 + (lane >> 5);
    int col = (lane & 31) * 4;
    float4 v = *(const float4*)&smf[row * 128 + (col ^ ((row & 4) << 2))];
    if (cvrow) {
      float cb = cvrow[row];
      v.x += cb; v.y += cb; v.z += cb; v.w += cb;
    }
    *(float4*)(dst + (size_t)row * ld + col) = v;
  }
}

// ---------- kF epilogue: 128 rows x 64 cols + cv ----------
__device__ __forceinline__ void epi_store64(f32x4 acc[4], float* smf, float* dst,
                                            const float* cvrow) {
  int t = threadIdx.x, lane = t & 63, wid = t >> 6;
  int wr = wid >> 2, wc = wid & 3;
#pragma unroll
  for (int m = 0; m < 4; ++m) {
    int rbase = wr * 64 + m * 16 + ((lane >> 4) << 2);
    int col = wc * 16 + (lane & 15);
#pragma unroll
    for (int e = 0; e < 4; ++e) {
      int row = rbase + e;
      smf[row * 64 + (col ^ ((row & 4) << 2))] = acc[m][e];
    }
  }
  __syncthreads();
#pragma unroll
  for (int it = 0; it < 4; ++it) {
    int slot = it * 512 + t;
    int row = slot >> 4, col = (slot & 15) * 4;
    float4 v = *(const float4*)&smf[row * 64 + (col ^ ((row & 4) << 2))];
    float cb = cvrow[row];
    v.x += cb; v.y += cb; v.z += cb; v.w += cb;
    *(float4*)(dst + (size_t)row * HW + col) = v;
  }
}

// ---------- kB: gram (192) + EF on-the-fly (8) + small vectors (13) ----------
__global__ __launch_bounds__(512) void kB(
    const float* __restrict__ X, float* __restrict__ Gp, float* __restrict__ psum2,
    const float* __restrict__ w0, const float* __restrict__ w1,
    const float* __restrict__ w2, const float* __restrict__ w3,
    const float* __restrict__ b0, const float* __restrict__ b1,
    const float* __restrict__ b2, unsigned short* __restrict__ Eh,
    unsigned short* __restrict__ El, float* __restrict__ Et,
    unsigned short* __restrict__ Fth, unsigned short* __restrict__ Ftl,
    float* __restrict__ Ff, float* __restrict__ vp, float* __restrict__ bpv,
    float* __restrict__ dlt, float* __restrict__ scal1) {
  __shared__ __align__(16) unsigned short sm[32768];
  int x = blockIdx.x, t = threadIdx.x;
  if (x < 192) {
    int tile = x % 3;
    int z = x / 3;
    int n = z >> 4, ks = z & 15;
    const float* Xn = X + (size_t)n * CD * HW;
    f32x4 acc[4][2];
    if (tile == 1) {
      gram_core<false, 4>(Xn, 0, 128, ks * 256, sm, acc, nullptr);
      epi_store(acc, (float*)sm, Gp + ((size_t)ks * NB + n) * CC + 128, CD, nullptr);
    } else {
      int i0 = (tile == 2) ? 128 : 0;
      float* psRow = psum2 + ((size_t)n * KSG + ks) * 256 + i0;
      gram_core<true, 4>(Xn, i0, i0, ks * 256, sm, acc, psRow);
      epi_store(acc, (float*)sm,
                Gp + ((size_t)ks * NB + n) * CC + (size_t)i0 * CD + i0, CD, nullptr);
    }
  } else if (x < 200) {
    int e = x - 192;
    int zc = e >> 2, q = e & 3;
    int i0 = (q >> 1) * 128, j0 = (q & 1) * 128;
    f32x4 acc[4][2];
#pragma unroll
    for (int m = 0; m < 4; ++m)
#pragma unroll
      for (int qq = 0; qq < 2; ++qq) acc[m][qq] = (f32x4){0.f, 0.f, 0.f, 0.f};
    for (int s = 0; s < 4; ++s) {
      int k0 = s * 64;
      if (zc == 0) stage_rowA(w3, CD, i0, k0, sm);
      else stage_colT(w2, CD, i0, k0, sm);
      stage_colT(zc ? w1 : w0, CD, j0, k0, sm + 16384);
      __syncthreads();
      mfma_body<16384>(sm, acc);
      __syncthreads();
    }
    unsigned short* oh = zc ? Fth : Eh;
    unsigned short* ol = zc ? Ftl : El;
    float* tf = zc ? Ff : Et;
    int lane = t & 63, wid = t >> 6, wr = wid >> 2, wc = wid & 3;
#pragma unroll
    for (int m = 0; m < 4; ++m) {
      int row = i0 + wr * 64 + m * 16 + ((lane >> 4) << 2);
#pragma unroll
      for (int q2 = 0; q2 < 2; ++q2) {
        int col = j0 + wc * 32 + q2 * 16 + (lane & 15);
#pragma unroll
        for (int e2 = 0; e2 < 4; ++e2) {
          float v = acc[m][q2][e2];
          unsigned short hh = f2bf(v), ll = f2bf(v - bfhi(hh));
          oh[(size_t)(row + e2) * CD + col] = hh;
          ol[(size_t)(row + e2) * CD + col] = ll;
          tf[(size_t)col * CD + row + e2] = v;
        }
      }
    }
  } else {
    int task = x - 200;
    if (task < 8) {
      float* vin = (float*)sm;
      int seg = task & 3;
      const float* Wm = (task < 4) ? w1 : w2;
      const float* v = (task < 4) ? b2 : b1;
      float* dst = (task < 4) ? (vp + seg * CD) : (bpv + seg * CD);
      if (t < 64) vin[t] = v[seg * 64 + t];
      __syncthreads();
      if (t < 256) {
        float a = 0.f;
#pragma unroll 16
        for (int kk = 0; kk < 64; ++kk)
          a += Wm[(size_t)(seg * 64 + kk) * CD + t] * vin[kk];
        dst[t] = a;
      }
    } else if (task < 12) {
      int lane = t & 63, wv = t >> 6;
      float4 bvv = *(const float4*)(b0 + lane * 4);
#pragma unroll
      for (int i = 0; i < 8; ++i) {
        int o = (task - 8) * 64 + wv * 8 + i;
        float4 v = *(const float4*)(w3 + (size_t)o * CD + lane * 4);
        float a = v.x * bvv.x + v.y * bvv.y + v.z * bvv.z + v.w * bvv.w;
        a += __shfl_xor(a, 1);  a += __shfl_xor(a, 2);  a += __shfl_xor(a, 4);
        a += __shfl_xor(a, 8);  a += __shfl_xor(a, 16); a += __shfl_xor(a, 32);
        if (lane == 0) dlt[o] = a;
      }
    } else if (task == 12) {
      float* red = (float*)sm;
      if (t < 256) red[t] = b1[t] * b2[t];
      __syncthreads();
      for (int off = 128; off > 0; off >>= 1) {
        if (t < off) red[t] += red[t + off];
        __syncthreads();
      }
      if (t == 0) scal1[0] = red[0];
    }
  }
}

// ---------- kC: gram reduce (+mirror) -> bf16 hi/lo + sag (100 blocks) ----------
__global__ __launch_bounds__(512) void kC(
    const float* __restrict__ Gp, unsigned short* __restrict__ Gh,
    unsigned short* __restrict__ Gl, const float* __restrict__ psum2,
    const float* __restrict__ vp, const float* __restrict__ Ff,
    const float* __restrict__ Et, float* __restrict__ alp, float* __restrict__ gam,
    float* __restrict__ scal0) {
  __shared__ float smf[512];
  int b = blockIdx.x, t = threadIdx.x;
  if (b < 96) {
#pragma unroll
    for (int s = 0; s < 4; ++s) {
      int f = b * 2048 + s * 512 + t;
      int b2 = f >> 8, tt = f & 255;
      int quad = b2 >> 8, r = b2 & 255, n = r >> 6;
      int idx = (r & 63) * 256 + tt;
      int i = (idx >> 7) + ((quad == 2) ? 128 : 0);
      int j = (idx & 127) + ((quad >= 1) ? 128 : 0);
      float a = 0.f;
#pragma unroll
      for (int ks = 0; ks < KSG; ++ks)
        a += Gp[((size_t)ks * NB + n) * CC + (size_t)i * CD + j];
      size_t o = (size_t)n * CC + (size_t)i * CD + j;
      unsigned short hh = f2bf(a), ll = f2bf(a - bfhi(hh));
      Gh[o] = hh; Gl[o] = ll;
      if (quad == 1) {
        size_t o2 = (size_t)n * CC + (size_t)j * CD + i;
        Gh[o2] = hh; Gl[o2] = ll;
      }
    }
  } else {
    int n = b - 96;
    float* ss = smf;
    float* red = ss + 256;
    float a = 0.f;
    if (t < 256) {
#pragma unroll
      for (int ks = 0; ks < KSG; ++ks) a += psum2[((size_t)n * KSG + ks) * 256 + t];
      ss[t] = a;
      red[t] = a * (vp[t] + vp[CD + t] + vp[2 * CD + t] + vp[3 * CD + t]);
    }
    __syncthreads();
    for (int off = 128; off > 0; off >>= 1) {
      if (t < off) red[t] += red[t + off];
      __syncthreads();
    }
    if (t == 0) scal0[n] = red[0];
    if (t < 256) {
      float al = 0.f, ga = 0.f;
#pragma unroll 16
      for (int k = 0; k < CD; ++k) {
        float sk = ss[k];
        al += Ff[(size_t)k * CD + t] * sk;
        ga += Et[(size_t)k * CD + t] * sk;
      }
      alp[n * CD + t] = al;
      gam[n * CD + t] = ga;
    }
  }
}

// ---------- kD1: Rm (16 blocks) + cv (4 blocks) ----------
__global__ __launch_bounds__(512) void kD1(
    const unsigned short* __restrict__ Eh, const unsigned short* __restrict__ El,
    const unsigned short* __restrict__ Gh, const unsigned short* __restrict__ Gl,
    unsigned short* __restrict__ Rh, unsigned short* __restrict__ Rl,
    const float* __restrict__ Et, const float* __restrict__ vp,
    const float* __restrict__ dlt, const float* __restrict__ gam,
    const float* __restrict__ scal0, const float* __restrict__ scal1,
    const float* __restrict__ b3, float* __restrict__ cv) {
  __shared__ __align__(16) unsigned short sm[32768];
  int b = blockIdx.x, t = threadIdx.x;
  if (b < 16) {
    int n = b >> 2, i0 = ((b >> 1) & 1) * 128, j0 = (b & 1) * 128;
    f32x4 acc[4][2];
    mfma_nt_core(Eh, El, Gh + (size_t)n * CC, Gl + (size_t)n * CC, i0, j0, sm, acc);
    int lane = t & 63, wid = t >> 6, wr = wid >> 2, wc = wid & 3;
#pragma unroll
    for (int m = 0; m < 4; ++m) {
      int row = i0 + wr * 64 + m * 16 + ((lane >> 4) << 2);
#pragma unroll
      for (int q = 0; q < 2; ++q) {
        int col = j0 + wc * 32 + q * 16 + (lane & 15);
#pragma unroll
        for (int e = 0; e < 4; ++e) {
          float v = acc[m][q][e];
          unsigned short hh = f2bf(v), ll = f2bf(v - bfhi(hh));
          Rh[(size_t)n * CC + (size_t)(row + e) * CD + col] = hh;
          Rl[(size_t)n * CC + (size_t)(row + e) * CD + col] = ll;
        }
      }
    }
  } else {
    int n = b - 16;
    float* vsh = (float*)sm;
    float* g1 = vsh + CD;
    if (t < CD) vsh[t] = vp[t] + vp[CD + t] + vp[2 * CD + t] + vp[3 * CD + t];
    __syncthreads();
    if (t < CD) {
      const unsigned short* GhN = Gh + (size_t)n * CC;
      const unsigned short* GlN = Gl + (size_t)n * CC;
      float a = 0.f;
#pragma unroll 8
      for (int k = 0; k < CD; ++k) {
        float g = bfhi(GhN[(size_t)k * CD + t]) + bfhi(GlN[(size_t)k * CD + t]);
        a += g * vsh[k];
      }
      g1[t] = a;
    }
    __syncthreads();
    if (t < CD) {
      float c2 = 0.f;
#pragma unroll 8
      for (int k = 0; k < CD; ++k) c2 += Et[(size_t)k * CD + t] * g1[k];
      cv[n * CD + t] = (c2 + scal0[n] * dlt[t] +
                        scal1[0] * (gam[n * CD + t] + (float)HW * dlt[t])) *
                           (1.0f / HW) +
                       b3[t];
    }
  }
}

// ---------- kD2: Atm (16 blocks) ----------
__global__ __launch_bounds__(512) void kD2(
    const unsigned short* __restrict__ Rh, const unsigned short* __restrict__ Rl,
    const unsigned short* __restrict__ Fth, const unsigned short* __restrict__ Ftl,
    unsigned short* __restrict__ Athi, unsigned short* __restrict__ Atlo,
    const float* __restrict__ dlt, const float* __restrict__ alp,
    const float* __restrict__ gam, const float* __restrict__ bpv) {
  __shared__ __align__(16) unsigned short sm[32768];
  int b = blockIdx.x, t = threadIdx.x;
  int n = b >> 2, i0 = ((b >> 1) & 1) * 128, j0 = (b & 1) * 128;
  f32x4 acc[4][2];
  mfma_nt_core(Rh + (size_t)n * CC, Rl + (size_t)n * CC, Fth, Ftl, i0, j0, sm, acc);
  int lane = t & 63, wid = t >> 6, wr = wid >> 2, wc = wid & 3;
#pragma unroll
  for (int m = 0; m < 4; ++m) {
    int row = i0 + wr * 64 + m * 16 + ((lane >> 4) << 2);
#pragma unroll
    for (int q = 0; q < 2; ++q) {
      int col = j0 + wc * 32 + q * 16 + (lane & 15);
      float bj = bpv[col] + bpv[CD + col] + bpv[2 * CD + col] + bpv[3 * CD + col];
      float aj = alp[n * CD + col];
#pragma unroll
      for (int e = 0; e < 4; ++e) {
        float di = dlt[row + e], gi = gam[n * CD + row + e];
        float v = (acc[m][q][e] + di * aj + gi * bj) * (1.0f / HW) + di * bj;
        unsigned short hh = f2bf(v), ll = f2bf(v - bfhi(hh));
        Athi[(size_t)n * CC + (size_t)(row + e) * CD + col] = hh;
        Atlo[(size_t)n * CC + (size_t)(row + e) * CD + col] = ll;
      }
    }
  }
}

// ---------- kF: out = At x X, 128-row x 64-col tiles, 512 blocks (2/CU TLP) ----------
__global__ __launch_bounds__(512) void kF(const unsigned short* __restrict__ Athi,
                                          const unsigned short* __restrict__ Atlo,
                                          const float* __restrict__ X,
                                          const float* __restrict__ cv,
                                          float* __restrict__ out) {
  int n = blockIdx.y;
  int x = blockIdx.x;
  int i0 = (x & 1) * 128;
  int j0 = (x >> 1) * 64;
  __shared__ __align__(16) unsigned short sm[24576];  // 48 KB: Ah|Al|Bh|Bl
  f32x4 acc[4];
  final_core64(Athi + (size_t)n * CC, Atlo + (size_t)n * CC, X + (size_t)n * CD * HW,
               i0, j0, sm, acc);
  epi_store64(acc, (float*)sm, out + (size_t)n * CD * HW + (size_t)i0 * HW + j0,
              cv + n * CD + i0);
}

extern "C" void kernel_launch(void* const* d_in, const int* in_sizes, int n_in,
                              void* d_out, int out_size, void* d_ws, size_t ws_size,
                              hipStream_t stream) {
  const float* X = (const float*)d_in[0];
  const float* w0 = (const float*)d_in[1];
  const float* b0 = (const float*)d_in[2];
  const float* w1 = (const float*)d_in[3];
  const float* b1 = (const float*)d_in[4];
  const float* w2 = (const float*)d_in[5];
  const float* b2 = (const float*)d_in[6];
  const float* w3 = (const float*)d_in[7];
  const float* b3 = (const float*)d_in[8];
  float* out = (float*)d_out;
  float* ws = (float*)d_ws;

  float* cv    = ws;
  float* alp   = ws + 1024;
  float* gam   = ws + 2048;
  float* dlt   = ws + 3072;
  float* vp    = ws + 4096;
  float* bpv   = ws + 5120;
  float* scal0 = ws + 6144;
  float* scal1 = ws + 6176;
  float* psum2 = ws + 8192;                    // NB*KSG*256 = 16384
  float* Et    = psum2 + 16384;
  float* Ff    = Et + CC;
  float* Gp    = Ff + CC;                      // KSG*NB*CC
  unsigned short* Eh   = (unsigned short*)(Gp + (size_t)KSG * NB * CC);
  unsigned short* El   = Eh + CC;
  unsigned short* Fth  = El + CC;
  unsigned short* Ftl  = Fth + CC;
  unsigned short* Gh   = Ftl + CC;
  unsigned short* Gl   = Gh + (size_t)NB * CC;
  unsigned short* Rh   = Gl + (size_t)NB * CC;
  unsigned short* Rl   = Rh + (size_t)NB * CC;
  unsigned short* Athi = Rl + (size_t)NB * CC;
  unsigned short* Atlo = Athi + (size_t)NB * CC;

  kB<<<dim3(213), 512, 0, stream>>>(X, Gp, psum2, w0, w1, w2, w3, b0, b1, b2, Eh, El,
                                    Et, Fth, Ftl, Ff, vp, bpv, dlt, scal1);
  kC<<<dim3(100), 512, 0, stream>>>(Gp, Gh, Gl, psum2, vp, Ff, Et, alp, gam, scal0);
  kD1<<<dim3(20), 512, 0, stream>>>(Eh, El, Gh, Gl, Rh, Rl, Et, vp, dlt, gam, scal0,
                                    scal1, b3, cv);
  kD2<<<dim3(16), 512, 0, stream>>>(Rh, Rl, Fth, Ftl, Athi, Atlo, dlt, alp, gam, bpv);
  kF<<<dim3(128, NB), 512, 0, stream>>>(Athi, Atlo, X, cv, out);
}

// Round 15
// 63.747 us; speedup vs baseline: 1.3568x; 1.1745x over previous
//
#include <hip/hip_runtime.h>

#define NB 4
#define CD 256
#define HW 4096
#define KSG 16
#define CC (CD * CD)

typedef __attribute__((ext_vector_type(8))) short bf16x8;
typedef __attribute__((ext_vector_type(4))) float f32x4;

__device__ inline unsigned short f2bf(float x) {
  unsigned int u = __float_as_uint(x);
  unsigned int r = (u + 0x7FFFu + ((u >> 16) & 1u)) >> 16;
  return (unsigned short)r;
}
__device__ inline float bfhi(unsigned short h) {
  return __uint_as_float(((unsigned int)h) << 16);
}
__device__ __forceinline__ void gload16(const unsigned short* g, unsigned short* l) {
  __builtin_amdgcn_global_load_lds((const __attribute__((address_space(1))) void*)g,
                                   (__attribute__((address_space(3))) void*)l, 16, 0, 0);
}

// ---------- MFMA body: A at sm[0]/sm[8192], B at sm[BOFF]/sm[BOFF+8192] ----------
template <int BOFF>
__device__ __forceinline__ void mfma_body(const unsigned short* sm, f32x4 acc[4][2]) {
  int t = threadIdx.x, lane = t & 63, wid = t >> 6;
  int wr = wid >> 2, wc = wid & 3;
  int lrow = lane & 15, lkb = lane >> 4;
#pragma unroll
  for (int ks2 = 0; ks2 < 2; ++ks2) {
    bf16x8 ah[4], al[4], bh[2], bl[2];
#pragma unroll
    for (int m = 0; m < 4; ++m) {
      int r = wr * 64 + m * 16 + lrow;
      int sw = ((ks2 * 4 + lkb) ^ (r & 7)) * 8;
      ah[m] = *(const bf16x8*)(sm + r * 64 + sw);
      al[m] = *(const bf16x8*)(sm + 8192 + r * 64 + sw);
    }
#pragma unroll
    for (int q = 0; q < 2; ++q) {
      int r = wc * 32 + q * 16 + lrow;
      int sw = ((ks2 * 4 + lkb) ^ (r & 7)) * 8;
      bh[q] = *(const bf16x8*)(sm + BOFF + r * 64 + sw);
      bl[q] = *(const bf16x8*)(sm + BOFF + 8192 + r * 64 + sw);
    }
#pragma unroll
    for (int m = 0; m < 4; ++m)
#pragma unroll
      for (int q = 0; q < 2; ++q) {
        acc[m][q] = __builtin_amdgcn_mfma_f32_16x16x32_bf16(ah[m], bh[q], acc[m][q], 0, 0, 0);
        acc[m][q] = __builtin_amdgcn_mfma_f32_16x16x32_bf16(ah[m], bl[q], acc[m][q], 0, 0, 0);
        acc[m][q] = __builtin_amdgcn_mfma_f32_16x16x32_bf16(al[m], bh[q], acc[m][q], 0, 0, 0);
      }
  }
}

// ---------- gram core: operands from X fp32, reg-prefetch; DIAG stages A only ----------
template <bool DIAG, int NSTEP>
__device__ __forceinline__ void gram_core(const float* __restrict__ Xn, int i0, int j0,
                                          int kBegin, unsigned short* sm,
                                          f32x4 acc[4][2], float* __restrict__ psumRow) {
  int t = threadIdx.x;
  int r16 = t >> 4, k4 = (t & 15) * 4;
  int kg = k4 >> 3, kr = k4 & 7;
#pragma unroll
  for (int m = 0; m < 4; ++m)
#pragma unroll
    for (int q = 0; q < 2; ++q) acc[m][q] = (f32x4){0.f, 0.f, 0.f, 0.f};
  float ps[4] = {0.f, 0.f, 0.f, 0.f};
  float4 av[4], bv[4];
#pragma unroll
  for (int j = 0; j < 4; ++j) {
    av[j] = *(const float4*)(Xn + (size_t)(i0 + j * 32 + r16) * HW + kBegin + k4);
    if (!DIAG)
      bv[j] = *(const float4*)(Xn + (size_t)(j0 + j * 32 + r16) * HW + kBegin + k4);
  }
#pragma unroll
  for (int s = 0; s < NSTEP; ++s) {
    float4 av2[4], bv2[4];
    if (s < NSTEP - 1) {
#pragma unroll
      for (int j = 0; j < 4; ++j) {
        av2[j] = *(const float4*)(Xn + (size_t)(i0 + j * 32 + r16) * HW + kBegin +
                                  (s + 1) * 64 + k4);
        if (!DIAG)
          bv2[j] = *(const float4*)(Xn + (size_t)(j0 + j * 32 + r16) * HW + kBegin +
                                    (s + 1) * 64 + k4);
      }
    }
#pragma unroll
    for (int j = 0; j < 4; ++j) {
      int r = j * 32 + r16;
      int off = r * 64 + ((kg ^ (r & 7)) << 3) + kr;
      ushort4 h, l;
      h.x = f2bf(av[j].x); l.x = f2bf(av[j].x - bfhi(h.x));
      h.y = f2bf(av[j].y); l.y = f2bf(av[j].y - bfhi(h.y));
      h.z = f2bf(av[j].z); l.z = f2bf(av[j].z - bfhi(h.z));
      h.w = f2bf(av[j].w); l.w = f2bf(av[j].w - bfhi(h.w));
      *(ushort4*)(sm + off) = h;
      *(ushort4*)(sm + 8192 + off) = l;
      ps[j] += av[j].x + av[j].y + av[j].z + av[j].w;
      if (!DIAG) {
        h.x = f2bf(bv[j].x); l.x = f2bf(bv[j].x - bfhi(h.x));
        h.y = f2bf(bv[j].y); l.y = f2bf(bv[j].y - bfhi(h.y));
        h.z = f2bf(bv[j].z); l.z = f2bf(bv[j].z - bfhi(h.z));
        h.w = f2bf(bv[j].w); l.w = f2bf(bv[j].w - bfhi(h.w));
        *(ushort4*)(sm + 16384 + off) = h;
        *(ushort4*)(sm + 24576 + off) = l;
      }
    }
    __syncthreads();
    mfma_body<DIAG ? 0 : 16384>(sm, acc);
    __syncthreads();
    if (s < NSTEP - 1) {
#pragma unroll
      for (int j = 0; j < 4; ++j) {
        av[j] = av2[j];
        if (!DIAG) bv[j] = bv2[j];
      }
    }
  }
  if (psumRow) {
#pragma unroll
    for (int j = 0; j < 4; ++j) {
      float v = ps[j];
      v += __shfl_xor(v, 1); v += __shfl_xor(v, 2);
      v += __shfl_xor(v, 4); v += __shfl_xor(v, 8);
      if ((t & 15) == 0) psumRow[j * 32 + r16] = v;
    }
  }
}

// ---------- ROW-stage: LDS[r][k] = W[r0+r][k0+k] (hi/lo) ----------
__device__ __forceinline__ void stage_rowA(const float* __restrict__ W, int ld, int r0,
                                           int k0, unsigned short* dst) {
  int t = threadIdx.x;
  int r16 = t >> 4, k4 = (t & 15) * 4;
  int kg = k4 >> 3, kr = k4 & 7;
#pragma unroll
  for (int j = 0; j < 4; ++j) {
    int r = j * 32 + r16;
    float4 v = *(const float4*)(W + (size_t)(r0 + r) * ld + k0 + k4);
    int off = r * 64 + ((kg ^ (r & 7)) << 3) + kr;
    ushort4 h, l;
    h.x = f2bf(v.x); l.x = f2bf(v.x - bfhi(h.x));
    h.y = f2bf(v.y); l.y = f2bf(v.y - bfhi(h.y));
    h.z = f2bf(v.z); l.z = f2bf(v.z - bfhi(h.z));
    h.w = f2bf(v.w); l.w = f2bf(v.w - bfhi(h.w));
    *(ushort4*)(dst + off) = h;
    *(ushort4*)(dst + 8192 + off) = l;
  }
}

// ---------- COL-stage (transpose): LDS[c][k] = W[k0+k][c0+c] (hi/lo), 128 cols ----------
__device__ __forceinline__ void stage_colT(const float* __restrict__ W, int ld, int c0,
                                           int k0, unsigned short* dst) {
  int t = threadIdx.x;
#pragma unroll
  for (int ee = 0; ee < 8; ++ee) {
    int flat = ee * 512 + t;
    int c2 = flat >> 7, p = flat & 127;
    const float* src = W + (size_t)(k0 + 2 * c2) * ld + c0 + p;
    float xa = src[0], xb = src[ld];
    int c = 2 * c2;
    int off = p * 64 + ((((c >> 3)) ^ (p & 7)) << 3) + (c & 7);
    unsigned short ha = f2bf(xa), hb = f2bf(xb);
    ushort2 hv; hv.x = ha; hv.y = hb;
    ushort2 lv; lv.x = f2bf(xa - bfhi(ha)); lv.y = f2bf(xb - bfhi(hb));
    *(ushort2*)(dst + off) = hv;
    *(ushort2*)(dst + 8192 + off) = lv;
  }
}

// ---------- kF MFMA body: A 128 rows @0/+8192, B 64 rows @16384/+4096 ----------
__device__ __forceinline__ void mfma_body64(const unsigned short* sm, f32x4 acc[4]) {
  int t = threadIdx.x, lane = t & 63, wid = t >> 6;
  int wr = wid >> 2, wc = wid & 3;
  int lrow = lane & 15, lkb = lane >> 4;
#pragma unroll
  for (int ks2 = 0; ks2 < 2; ++ks2) {
    bf16x8 ah[4], al[4], bh, bl;
#pragma unroll
    for (int m = 0; m < 4; ++m) {
      int r = wr * 64 + m * 16 + lrow;
      int sw = ((ks2 * 4 + lkb) ^ (r & 7)) * 8;
      ah[m] = *(const bf16x8*)(sm + r * 64 + sw);
      al[m] = *(const bf16x8*)(sm + 8192 + r * 64 + sw);
    }
    {
      int r = wc * 16 + lrow;
      int sw = ((ks2 * 4 + lkb) ^ (r & 7)) * 8;
      bh = *(const bf16x8*)(sm + 16384 + r * 64 + sw);
      bl = *(const bf16x8*)(sm + 20480 + r * 64 + sw);
    }
#pragma unroll
    for (int m = 0; m < 4; ++m) {
      acc[m] = __builtin_amdgcn_mfma_f32_16x16x32_bf16(ah[m], bh, acc[m], 0, 0, 0);
      acc[m] = __builtin_amdgcn_mfma_f32_16x16x32_bf16(ah[m], bl, acc[m], 0, 0, 0);
      acc[m] = __builtin_amdgcn_mfma_f32_16x16x32_bf16(al[m], bh, acc[m], 0, 0, 0);
    }
  }
}

// ---------- kF core (64-col B): A = At via gload16; B = X fp32 transpose-staged ----------
__device__ __forceinline__ void final_core64(const unsigned short* __restrict__ aH,
                                             const unsigned short* __restrict__ aL,
                                             const float* __restrict__ Xn, int i0, int j0,
                                             unsigned short* sm, f32x4 acc[4]) {
  int t = threadIdx.x, lane = t & 63, wid = t >> 6;
  const unsigned short* ap = (wid & 4) ? aL : aH;
  unsigned short* ldsA = sm + ((wid & 4) ? 8192 : 0);
  int rsub = lane >> 3;
  int gc = (lane & 7) ^ rsub;
  int gq = wid & 3;
#pragma unroll
  for (int m = 0; m < 4; ++m) acc[m] = (f32x4){0.f, 0.f, 0.f, 0.f};
  float xa[4], xb[4];
#pragma unroll
  for (int s2 = 0; s2 < 4; ++s2) {
    int g = gq * 4 + s2;
    gload16(ap + (size_t)(i0 + g * 8 + rsub) * CD + gc * 8, ldsA + g * 512);
  }
#pragma unroll
  for (int ee = 0; ee < 4; ++ee) {
    int flat = ee * 512 + t;
    int c2 = flat >> 6, p = flat & 63;
    const float* src = Xn + (size_t)(2 * c2) * HW + j0 + p;
    xa[ee] = src[0];
    xb[ee] = src[HW];
  }
#pragma unroll
  for (int s = 0; s < 4; ++s) {
#pragma unroll
    for (int ee = 0; ee < 4; ++ee) {
      int flat = ee * 512 + t;
      int c2 = flat >> 6, p = flat & 63;
      int c = 2 * c2;
      int off = p * 64 + ((((c >> 3)) ^ (p & 7)) << 3) + (c & 7);
      unsigned short ha = f2bf(xa[ee]), hb = f2bf(xb[ee]);
      ushort2 hv; hv.x = ha; hv.y = hb;
      ushort2 lv; lv.x = f2bf(xa[ee] - bfhi(ha)); lv.y = f2bf(xb[ee] - bfhi(hb));
      *(ushort2*)(sm + 16384 + off) = hv;
      *(ushort2*)(sm + 20480 + off) = lv;
    }
    float xa2[4], xb2[4];
    if (s < 3) {
#pragma unroll
      for (int ee = 0; ee < 4; ++ee) {
        int flat = ee * 512 + t;
        int c2 = flat >> 6, p = flat & 63;
        const float* src = Xn + (size_t)((s + 1) * 64 + 2 * c2) * HW + j0 + p;
        xa2[ee] = src[0];
        xb2[ee] = src[HW];
      }
    }
    __syncthreads();
    mfma_body64(sm, acc);
    __syncthreads();
    if (s < 3) {
#pragma unroll
      for (int s2 = 0; s2 < 4; ++s2) {
        int g = gq * 4 + s2;
        gload16(ap + (size_t)(i0 + g * 8 + rsub) * CD + (s + 1) * 64 + gc * 8,
                ldsA + g * 512);
      }
#pragma unroll
      for (int ee = 0; ee < 4; ++ee) { xa[ee] = xa2[ee]; xb[ee] = xb2[ee]; }
    }
  }
}

// ---------- coalesced fp32 epilogue (128x128 tile, kB) ----------
__device__ __forceinline__ void epi_store(f32x4 acc[4][2], float* smf, float* dst,
                                          int ld, const float* cvrow) {
  int t = threadIdx.x, lane = t & 63, wid = t >> 6;
  int wr = wid >> 2, wc = wid & 3;
#pragma unroll
  for (int m = 0; m < 4; ++m) {
    int rbase = wr * 64 + m * 16 + ((lane >> 4) << 2);
#pragma unroll
    for (int q = 0; q < 2; ++q) {
      int col = wc * 32 + q * 16 + (lane & 15);
#pragma unroll
      for (int e = 0; e < 4; ++e) {
        int row = rbase + e;
        smf[row * 128 + (col ^ ((row & 4) << 2))] = acc[m][q][e];
      }
    }
  }
  __syncthreads();
#pragma unroll
  for (int it = 0; it < 8; ++it) {
    int row = it * 16 + wid * 2 + (lane >> 5);
    int col = (lane & 31) * 4;
    float4 v = *(const float4*)&smf[row * 128 + (col ^ ((row & 4) << 2))];
    if (cvrow) {
      float cb = cvrow[row];
      v.x += cb; v.y += cb; v.z += cb; v.w += cb;
    }
    *(float4*)(dst + (size_t)row * ld + col) = v;
  }
}

// ---------- kF epilogue: 128 rows x 64 cols + cv ----------
__device__ __forceinline__ void epi_store64(f32x4 acc[4], float* smf, float* dst,
                                            const float* cvrow) {
  int t = threadIdx.x, lane = t & 63, wid = t >> 6;
  int wr = wid >> 2, wc = wid & 3;
#pragma unroll
  for (int m = 0; m < 4; ++m) {
    int rbase = wr * 64 + m * 16 + ((lane >> 4) << 2);
    int col = wc * 16 + (lane & 15);
#pragma unroll
    for (int e = 0; e < 4; ++e) {
      int row = rbase + e;
      smf[row * 64 + (col ^ ((row & 4) << 2))] = acc[m][e];
    }
  }
  __syncthreads();
#pragma unroll
  for (int it = 0; it < 4; ++it) {
    int slot = it * 512 + t;
    int row = slot >> 4, col = (slot & 15) * 4;
    float4 v = *(const float4*)&smf[row * 64 + (col ^ ((row & 4) << 2))];
    float cb = cvrow[row];
    v.x += cb; v.y += cb; v.z += cb; v.w += cb;
    *(float4*)(dst + (size_t)row * HW + col) = v;
  }
}

// ---------- kB: gram (192) + EF on-the-fly (8) + small vectors (13) ----------
__global__ __launch_bounds__(512) void kB(
    const float* __restrict__ X, float* __restrict__ Gp, float* __restrict__ psum2,
    const float* __restrict__ w0, const float* __restrict__ w1,
    const float* __restrict__ w2, const float* __restrict__ w3,
    const float* __restrict__ b0, const float* __restrict__ b1,
    const float* __restrict__ b2, unsigned short* __restrict__ Eh,
    unsigned short* __restrict__ El, float* __restrict__ Et,
    unsigned short* __restrict__ Fth, unsigned short* __restrict__ Ftl,
    float* __restrict__ Ff, float* __restrict__ vp, float* __restrict__ bpv,
    float* __restrict__ dlt, float* __restrict__ scal1) {
  __shared__ __align__(16) unsigned short sm[32768];
  int x = blockIdx.x, t = threadIdx.x;
  if (x < 192) {
    int tile = x % 3;
    int z = x / 3;
    int n = z >> 4, ks = z & 15;
    const float* Xn = X + (size_t)n * CD * HW;
    f32x4 acc[4][2];
    if (tile == 1) {
      gram_core<false, 4>(Xn, 0, 128, ks * 256, sm, acc, nullptr);
      epi_store(acc, (float*)sm, Gp + ((size_t)ks * NB + n) * CC + 128, CD, nullptr);
    } else {
      int i0 = (tile == 2) ? 128 : 0;
      float* psRow = psum2 + ((size_t)n * KSG + ks) * 256 + i0;
      gram_core<true, 4>(Xn, i0, i0, ks * 256, sm, acc, psRow);
      epi_store(acc, (float*)sm,
                Gp + ((size_t)ks * NB + n) * CC + (size_t)i0 * CD + i0, CD, nullptr);
    }
  } else if (x < 200) {
    int e = x - 192;
    int zc = e >> 2, q = e & 3;
    int i0 = (q >> 1) * 128, j0 = (q & 1) * 128;
    f32x4 acc[4][2];
#pragma unroll
    for (int m = 0; m < 4; ++m)
#pragma unroll
      for (int qq = 0; qq < 2; ++qq) acc[m][qq] = (f32x4){0.f, 0.f, 0.f, 0.f};
    for (int s = 0; s < 4; ++s) {
      int k0 = s * 64;
      if (zc == 0) stage_rowA(w3, CD, i0, k0, sm);
      else stage_colT(w2, CD, i0, k0, sm);
      stage_colT(zc ? w1 : w0, CD, j0, k0, sm + 16384);
      __syncthreads();
      mfma_body<16384>(sm, acc);
      __syncthreads();
    }
    unsigned short* oh = zc ? Fth : Eh;
    unsigned short* ol = zc ? Ftl : El;
    float* tf = zc ? Ff : Et;
    int lane = t & 63, wid = t >> 6, wr = wid >> 2, wc = wid & 3;
#pragma unroll
    for (int m = 0; m < 4; ++m) {
      int row = i0 + wr * 64 + m * 16 + ((lane >> 4) << 2);
#pragma unroll
      for (int q2 = 0; q2 < 2; ++q2) {
        int col = j0 + wc * 32 + q2 * 16 + (lane & 15);
#pragma unroll
        for (int e2 = 0; e2 < 4; ++e2) {
          float v = acc[m][q2][e2];
          unsigned short hh = f2bf(v), ll = f2bf(v - bfhi(hh));
          oh[(size_t)(row + e2) * CD + col] = hh;
          ol[(size_t)(row + e2) * CD + col] = ll;
          tf[(size_t)col * CD + row + e2] = v;
        }
      }
    }
  } else {
    int task = x - 200;
    if (task < 8) {
      float* vin = (float*)sm;
      int seg = task & 3;
      const float* Wm = (task < 4) ? w1 : w2;
      const float* v = (task < 4) ? b2 : b1;
      float* dst = (task < 4) ? (vp + seg * CD) : (bpv + seg * CD);
      if (t < 64) vin[t] = v[seg * 64 + t];
      __syncthreads();
      if (t < 256) {
        float a = 0.f;
#pragma unroll 16
        for (int kk = 0; kk < 64; ++kk)
          a += Wm[(size_t)(seg * 64 + kk) * CD + t] * vin[kk];
        dst[t] = a;
      }
    } else if (task < 12) {
      int lane = t & 63, wv = t >> 6;
      float4 bvv = *(const float4*)(b0 + lane * 4);
#pragma unroll
      for (int i = 0; i < 8; ++i) {
        int o = (task - 8) * 64 + wv * 8 + i;
        float4 v = *(const float4*)(w3 + (size_t)o * CD + lane * 4);
        float a = v.x * bvv.x + v.y * bvv.y + v.z * bvv.z + v.w * bvv.w;
        a += __shfl_xor(a, 1);  a += __shfl_xor(a, 2);  a += __shfl_xor(a, 4);
        a += __shfl_xor(a, 8);  a += __shfl_xor(a, 16); a += __shfl_xor(a, 32);
        if (lane == 0) dlt[o] = a;
      }
    } else if (task == 12) {
      float* red = (float*)sm;
      if (t < 256) red[t] = b1[t] * b2[t];
      __syncthreads();
      for (int off = 128; off > 0; off >>= 1) {
        if (t < off) red[t] += red[t + off];
        __syncthreads();
      }
      if (t == 0) scal1[0] = red[0];
    }
  }
}

// ---------- kC: gram reduce (+mirror) -> bf16 hi/lo + sag (100 blocks) ----------
__global__ __launch_bounds__(512) void kC(
    const float* __restrict__ Gp, unsigned short* __restrict__ Gh,
    unsigned short* __restrict__ Gl, const float* __restrict__ psum2,
    const float* __restrict__ vp, const float* __restrict__ Ff,
    const float* __restrict__ Et, float* __restrict__ alp, float* __restrict__ gam,
    float* __restrict__ scal0) {
  __shared__ float smf[512];
  int b = blockIdx.x, t = threadIdx.x;
  if (b < 96) {
#pragma unroll
    for (int s = 0; s < 4; ++s) {
      int f = b * 2048 + s * 512 + t;
      int b2 = f >> 8, tt = f & 255;
      int quad = b2 >> 8, r = b2 & 255, n = r >> 6;
      int idx = (r & 63) * 256 + tt;
      int i = (idx >> 7) + ((quad == 2) ? 128 : 0);
      int j = (idx & 127) + ((quad >= 1) ? 128 : 0);
      float a = 0.f;
#pragma unroll
      for (int ks = 0; ks < KSG; ++ks)
        a += Gp[((size_t)ks * NB + n) * CC + (size_t)i * CD + j];
      size_t o = (size_t)n * CC + (size_t)i * CD + j;
      unsigned short hh = f2bf(a), ll = f2bf(a - bfhi(hh));
      Gh[o] = hh; Gl[o] = ll;
      if (quad == 1) {
        size_t o2 = (size_t)n * CC + (size_t)j * CD + i;
        Gh[o2] = hh; Gl[o2] = ll;
      }
    }
  } else {
    int n = b - 96;
    float* ss = smf;
    float* red = ss + 256;
    float a = 0.f;
    if (t < 256) {
#pragma unroll
      for (int ks = 0; ks < KSG; ++ks) a += psum2[((size_t)n * KSG + ks) * 256 + t];
      ss[t] = a;
      red[t] = a * (vp[t] + vp[CD + t] + vp[2 * CD + t] + vp[3 * CD + t]);
    }
    __syncthreads();
    for (int off = 128; off > 0; off >>= 1) {
      if (t < off) red[t] += red[t + off];
      __syncthreads();
    }
    if (t == 0) scal0[n] = red[0];
    if (t < 256) {
      float al = 0.f, ga = 0.f;
#pragma unroll 16
      for (int k = 0; k < CD; ++k) {
        float sk = ss[k];
        al += Ff[(size_t)k * CD + t] * sk;
        ga += Et[(size_t)k * CD + t] * sk;
      }
      alp[n * CD + t] = al;
      gam[n * CD + t] = ga;
    }
  }
}

// ---------- kD: fused At = (E[i-slice]*G)*Ft + rank-1 (32 blocks) + cv (4 blocks) ----------
// LDS map (ushort): Astage 0..8191 (Ah 0, Al 4096), Bstage 8192..24575 (Bh 8192, Bl 16384),
//                   Th 24576..40959 (4 chunks x [64][64]), Tl 40960..57343.
__global__ __launch_bounds__(512) void kD(
    const unsigned short* __restrict__ Eh, const unsigned short* __restrict__ El,
    const unsigned short* __restrict__ Gh, const unsigned short* __restrict__ Gl,
    const unsigned short* __restrict__ Fth, const unsigned short* __restrict__ Ftl,
    unsigned short* __restrict__ Athi, unsigned short* __restrict__ Atlo,
    const float* __restrict__ dlt, const float* __restrict__ alp,
    const float* __restrict__ gam, const float* __restrict__ bpv,
    const float* __restrict__ Et, const float* __restrict__ vp,
    const float* __restrict__ scal0, const float* __restrict__ scal1,
    const float* __restrict__ b3, float* __restrict__ cv) {
  __shared__ __align__(16) unsigned short sm[57344];
  int b = blockIdx.x, t = threadIdx.x;
  if (b < 32) {
    int n = b >> 3, i0 = ((b >> 1) & 3) * 64, j0 = (b & 1) * 128;
    int lane = t & 63, wid = t >> 6;
    int wr = wid >> 2, wc = wid & 3;
    int lrow = lane & 15, lkb = lane >> 4;
    int rsub = lane >> 3, gcx = (lane & 7) ^ rsub;
    const unsigned short* GhN = Gh + (size_t)n * CC;
    const unsigned short* GlN = Gl + (size_t)n * CC;
    // ---- phase 1: T = E[i0..i0+64] * G  (acc1[m][half][q]) ----
    f32x4 acc1[2][2][2];
#pragma unroll
    for (int m = 0; m < 2; ++m)
#pragma unroll
      for (int h = 0; h < 2; ++h)
#pragma unroll
        for (int q = 0; q < 2; ++q) acc1[m][h][q] = (f32x4){0.f, 0.f, 0.f, 0.f};
    for (int k0 = 0; k0 < 256; k0 += 64) {
      // sub-phase 0: stage E rows + G rows 0..127
#pragma unroll
      for (int u = 0; u < 6; ++u) {
        int flat = wid * 6 + u;
        if (flat < 8)
          gload16(Eh + (size_t)(i0 + flat * 8 + rsub) * CD + k0 + gcx * 8, sm + flat * 512);
        else if (flat < 16)
          gload16(El + (size_t)(i0 + (flat - 8) * 8 + rsub) * CD + k0 + gcx * 8,
                  sm + 4096 + (flat - 8) * 512);
        else if (flat < 32)
          gload16(GhN + (size_t)((flat - 16) * 8 + rsub) * CD + k0 + gcx * 8,
                  sm + 8192 + (flat - 16) * 512);
        else
          gload16(GlN + (size_t)((flat - 32) * 8 + rsub) * CD + k0 + gcx * 8,
                  sm + 16384 + (flat - 32) * 512);
      }
      __syncthreads();
#pragma unroll
      for (int ks2 = 0; ks2 < 2; ++ks2) {
        bf16x8 ah[2], al[2], bh[2], bl[2];
#pragma unroll
        for (int m = 0; m < 2; ++m) {
          int r = wr * 32 + m * 16 + lrow;
          int sw = ((ks2 * 4 + lkb) ^ (r & 7)) * 8;
          ah[m] = *(const bf16x8*)(sm + r * 64 + sw);
          al[m] = *(const bf16x8*)(sm + 4096 + r * 64 + sw);
        }
#pragma unroll
        for (int q = 0; q < 2; ++q) {
          int rr = wc * 32 + q * 16 + lrow;
          int sw = ((ks2 * 4 + lkb) ^ (rr & 7)) * 8;
          bh[q] = *(const bf16x8*)(sm + 8192 + rr * 64 + sw);
          bl[q] = *(const bf16x8*)(sm + 16384 + rr * 64 + sw);
        }
#pragma unroll
        for (int m = 0; m < 2; ++m)
#pragma unroll
          for (int q = 0; q < 2; ++q) {
            acc1[m][0][q] = __builtin_amdgcn_mfma_f32_16x16x32_bf16(ah[m], bh[q], acc1[m][0][q], 0, 0, 0);
            acc1[m][0][q] = __builtin_amdgcn_mfma_f32_16x16x32_bf16(ah[m], bl[q], acc1[m][0][q], 0, 0, 0);
            acc1[m][0][q] = __builtin_amdgcn_mfma_f32_16x16x32_bf16(al[m], bh[q], acc1[m][0][q], 0, 0, 0);
          }
      }
      __syncthreads();
      // sub-phase 1: stage G rows 128..255 (A stays valid)
#pragma unroll
      for (int u = 0; u < 4; ++u) {
        int flat = wid * 4 + u;
        if (flat < 16)
          gload16(GhN + (size_t)(128 + flat * 8 + rsub) * CD + k0 + gcx * 8,
                  sm + 8192 + flat * 512);
        else
          gload16(GlN + (size_t)(128 + (flat - 16) * 8 + rsub) * CD + k0 + gcx * 8,
                  sm + 16384 + (flat - 16) * 512);
      }
      __syncthreads();
#pragma unroll
      for (int ks2 = 0; ks2 < 2; ++ks2) {
        bf16x8 ah[2], al[2], bh[2], bl[2];
#pragma unroll
        for (int m = 0; m < 2; ++m) {
          int r = wr * 32 + m * 16 + lrow;
          int sw = ((ks2 * 4 + lkb) ^ (r & 7)) * 8;
          ah[m] = *(const bf16x8*)(sm + r * 64 + sw);
          al[m] = *(const bf16x8*)(sm + 4096 + r * 64 + sw);
        }
#pragma unroll
        for (int q = 0; q < 2; ++q) {
          int rr = wc * 32 + q * 16 + lrow;
          int sw = ((ks2 * 4 + lkb) ^ (rr & 7)) * 8;
          bh[q] = *(const bf16x8*)(sm + 8192 + rr * 64 + sw);
          bl[q] = *(const bf16x8*)(sm + 16384 + rr * 64 + sw);
        }
#pragma unroll
        for (int m = 0; m < 2; ++m)
#pragma unroll
          for (int q = 0; q < 2; ++q) {
            acc1[m][1][q] = __builtin_amdgcn_mfma_f32_16x16x32_bf16(ah[m], bh[q], acc1[m][1][q], 0, 0, 0);
            acc1[m][1][q] = __builtin_amdgcn_mfma_f32_16x16x32_bf16(ah[m], bl[q], acc1[m][1][q], 0, 0, 0);
            acc1[m][1][q] = __builtin_amdgcn_mfma_f32_16x16x32_bf16(al[m], bh[q], acc1[m][1][q], 0, 0, 0);
          }
      }
      __syncthreads();
    }
    // ---- write T (64 x 256) hi/lo into chunked swizzled LDS ----
#pragma unroll
    for (int m = 0; m < 2; ++m)
#pragma unroll
      for (int h = 0; h < 2; ++h)
#pragma unroll
        for (int q = 0; q < 2; ++q)
#pragma unroll
          for (int e = 0; e < 4; ++e) {
            int row = wr * 32 + m * 16 + ((lane >> 4) << 2) + e;
            int col = h * 128 + wc * 32 + q * 16 + (lane & 15);
            float v = acc1[m][h][q][e];
            unsigned short hh = f2bf(v), ll = f2bf(v - bfhi(hh));
            int c = col >> 6, ccv = col & 63;
            int off = c * 4096 + row * 64 + (((ccv >> 3) ^ (row & 7)) << 3) + (ccv & 7);
            sm[24576 + off] = hh;
            sm[40960 + off] = ll;
          }
    __syncthreads();
    // ---- phase 2: At-slice = T * Ft[j0..j0+128]  (acc2[m][q]) ----
    f32x4 acc2[2][2];
#pragma unroll
    for (int m = 0; m < 2; ++m)
#pragma unroll
      for (int q = 0; q < 2; ++q) acc2[m][q] = (f32x4){0.f, 0.f, 0.f, 0.f};
    for (int c = 0; c < 4; ++c) {
#pragma unroll
      for (int u = 0; u < 4; ++u) {
        int flat = wid * 4 + u;
        if (flat < 16)
          gload16(Fth + (size_t)(j0 + flat * 8 + rsub) * CD + c * 64 + gcx * 8,
                  sm + 8192 + flat * 512);
        else
          gload16(Ftl + (size_t)(j0 + (flat - 16) * 8 + rsub) * CD + c * 64 + gcx * 8,
                  sm + 16384 + (flat - 16) * 512);
      }
      __syncthreads();
#pragma unroll
      for (int ks2 = 0; ks2 < 2; ++ks2) {
        bf16x8 ah[2], al[2], bh[2], bl[2];
#pragma unroll
        for (int m = 0; m < 2; ++m) {
          int r = wr * 32 + m * 16 + lrow;
          int sw = ((ks2 * 4 + lkb) ^ (r & 7)) * 8;
          ah[m] = *(const bf16x8*)(sm + 24576 + c * 4096 + r * 64 + sw);
          al[m] = *(const bf16x8*)(sm + 40960 + c * 4096 + r * 64 + sw);
        }
#pragma unroll
        for (int q = 0; q < 2; ++q) {
          int rr = wc * 32 + q * 16 + lrow;
          int sw = ((ks2 * 4 + lkb) ^ (rr & 7)) * 8;
          bh[q] = *(const bf16x8*)(sm + 8192 + rr * 64 + sw);
          bl[q] = *(const bf16x8*)(sm + 16384 + rr * 64 + sw);
        }
#pragma unroll
        for (int m = 0; m < 2; ++m)
#pragma unroll
          for (int q = 0; q < 2; ++q) {
            acc2[m][q] = __builtin_amdgcn_mfma_f32_16x16x32_bf16(ah[m], bh[q], acc2[m][q], 0, 0, 0);
            acc2[m][q] = __builtin_amdgcn_mfma_f32_16x16x32_bf16(ah[m], bl[q], acc2[m][q], 0, 0, 0);
            acc2[m][q] = __builtin_amdgcn_mfma_f32_16x16x32_bf16(al[m], bh[q], acc2[m][q], 0, 0, 0);
          }
      }
      __syncthreads();
    }
    // ---- epilogue: rank-1 terms, write Athi/Atlo ----
#pragma unroll
    for (int m = 0; m < 2; ++m) {
      int row = i0 + wr * 32 + m * 16 + ((lane >> 4) << 2);
#pragma unroll
      for (int q = 0; q < 2; ++q) {
        int col = j0 + wc * 32 + q * 16 + (lane & 15);
        float bj = bpv[col] + bpv[CD + col] + bpv[2 * CD + col] + bpv[3 * CD + col];
        float aj = alp[n * CD + col];
#pragma unroll
        for (int e = 0; e < 4; ++e) {
          float di = dlt[row + e], gi = gam[n * CD + row + e];
          float v = (acc2[m][q][e] + di * aj + gi * bj) * (1.0f / HW) + di * bj;
          unsigned short hh = f2bf(v), ll = f2bf(v - bfhi(hh));
          Athi[(size_t)n * CC + (size_t)(row + e) * CD + col] = hh;
          Atlo[(size_t)n * CC + (size_t)(row + e) * CD + col] = ll;
        }
      }
    }
  } else {
    // ---- cv blocks ----
    int n = b - 32;
    float* vsh = (float*)sm;
    float* g1 = vsh + CD;
    if (t < CD) vsh[t] = vp[t] + vp[CD + t] + vp[2 * CD + t] + vp[3 * CD + t];
    __syncthreads();
    if (t < CD) {
      const unsigned short* GhN = Gh + (size_t)n * CC;
      const unsigned short* GlN = Gl + (size_t)n * CC;
      float a = 0.f;
#pragma unroll 8
      for (int k = 0; k < CD; ++k) {
        float g = bfhi(GhN[(size_t)k * CD + t]) + bfhi(GlN[(size_t)k * CD + t]);
        a += g * vsh[k];
      }
      g1[t] = a;
    }
    __syncthreads();
    if (t < CD) {
      float c2 = 0.f;
#pragma unroll 8
      for (int k = 0; k < CD; ++k) c2 += Et[(size_t)k * CD + t] * g1[k];
      cv[n * CD + t] = (c2 + scal0[n] * dlt[t] +
                        scal1[0] * (gam[n * CD + t] + (float)HW * dlt[t])) *
                           (1.0f / HW) +
                       b3[t];
    }
  }
}

// ---------- kF: out = At x X, 128-row x 64-col tiles, 512 blocks ----------
__global__ __launch_bounds__(512) void kF(const unsigned short* __restrict__ Athi,
                                          const unsigned short* __restrict__ Atlo,
                                          const float* __restrict__ X,
                                          const float* __restrict__ cv,
                                          float* __restrict__ out) {
  int n = blockIdx.y;
  int x = blockIdx.x;
  int i0 = (x & 1) * 128;
  int j0 = (x >> 1) * 64;
  __shared__ __align__(16) unsigned short sm[24576];
  f32x4 acc[4];
  final_core64(Athi + (size_t)n * CC, Atlo + (size_t)n * CC, X + (size_t)n * CD * HW,
               i0, j0, sm, acc);
  epi_store64(acc, (float*)sm, out + (size_t)n * CD * HW + (size_t)i0 * HW + j0,
              cv + n * CD + i0);
}

extern "C" void kernel_launch(void* const* d_in, const int* in_sizes, int n_in,
                              void* d_out, int out_size, void* d_ws, size_t ws_size,
                              hipStream_t stream) {
  const float* X = (const float*)d_in[0];
  const float* w0 = (const float*)d_in[1];
  const float* b0 = (const float*)d_in[2];
  const float* w1 = (const float*)d_in[3];
  const float* b1 = (const float*)d_in[4];
  const float* w2 = (const float*)d_in[5];
  const float* b2 = (const float*)d_in[6];
  const float* w3 = (const float*)d_in[7];
  const float* b3 = (const float*)d_in[8];
  float* out = (float*)d_out;
  float* ws = (float*)d_ws;

  float* cv    = ws;
  float* alp   = ws + 1024;
  float* gam   = ws + 2048;
  float* dlt   = ws + 3072;
  float* vp    = ws + 4096;
  float* bpv   = ws + 5120;
  float* scal0 = ws + 6144;
  float* scal1 = ws + 6176;
  float* psum2 = ws + 8192;                    // NB*KSG*256 = 16384
  float* Et    = psum2 + 16384;
  float* Ff    = Et + CC;
  float* Gp    = Ff + CC;                      // KSG*NB*CC
  unsigned short* Eh   = (unsigned short*)(Gp + (size_t)KSG * NB * CC);
  unsigned short* El   = Eh + CC;
  unsigned short* Fth  = El + CC;
  unsigned short* Ftl  = Fth + CC;
  unsigned short* Gh   = Ftl + CC;
  unsigned short* Gl   = Gh + (size_t)NB * CC;
  unsigned short* Athi = Gl + (size_t)NB * CC;
  unsigned short* Atlo = Athi + (size_t)NB * CC;

  kB<<<dim3(213), 512, 0, stream>>>(X, Gp, psum2, w0, w1, w2, w3, b0, b1, b2, Eh, El,
                                    Et, Fth, Ftl, Ff, vp, bpv, dlt, scal1);
  kC<<<dim3(100), 512, 0, stream>>>(Gp, Gh, Gl, psum2, vp, Ff, Et, alp, gam, scal0);
  kD<<<dim3(36), 512, 0, stream>>>(Eh, El, Gh, Gl, Fth, Ftl, Athi, Atlo, dlt, alp, gam,
                                   bpv, Et, vp, scal0, scal1, b3, cv);
  kF<<<dim3(128, NB), 512, 0, stream>>>(Athi, Atlo, X, cv, out);
}